// Round 2
// baseline (2704.275 us; speedup 1.0000x reference)
//
#include <hip/hip_runtime.h>
#include <hip/hip_bf16.h>

typedef short bf16x8 __attribute__((ext_vector_type(8)));
typedef float f32x4 __attribute__((ext_vector_type(4)));

// f32 -> bf16 round-to-nearest-even, as raw bits
__device__ __forceinline__ unsigned short f2b(float f) {
  union { float f; unsigned u; } v; v.f = f;
  unsigned r = v.u + 0x7FFF + ((v.u >> 16) & 1);
  return (unsigned short)(r >> 16);
}

// bf16 raw bits -> f32
__device__ __forceinline__ float b2f(unsigned short u) {
  union { unsigned u; float f; } v; v.u = ((unsigned)u) << 16;
  return v.f;
}

// async global->LDS, 16B per lane; LDS dest = base + lane*16 (wave-uniform base)
__device__ __forceinline__ void async_b128(const void* g, void* l) {
  __builtin_amdgcn_global_load_lds(
      (const __attribute__((address_space(1))) unsigned int*)g,
      (__attribute__((address_space(3))) unsigned int*)l, 16, 0, 0);
}

// ---------------- zero-fill helpers (no hipMemsetAsync in capture) ----------
__global__ void zero_f32_kernel(float* __restrict__ p, long n) {
  long i = (long)blockIdx.x * blockDim.x + threadIdx.x;
  long stride = (long)gridDim.x * blockDim.x;
  for (; i < n; i += stride) p[i] = 0.f;
}
__global__ void zero_i32_kernel(int* __restrict__ p, int n) {
  int i = blockIdx.x * blockDim.x + threadIdx.x;
  if (i < n) p[i] = 0;
}

// ---------------- preproc: f32 -> bf16 flat convert -------------------------
__global__ __launch_bounds__(256) void convert_bf16_kernel(
    const float* __restrict__ src, unsigned short* __restrict__ dst, long n8) {
  long i = (long)blockIdx.x * blockDim.x + threadIdx.x;
  long stride = (long)gridDim.x * blockDim.x;
  for (; i < n8; i += stride) {
    const float* s = src + i * 8;
    float4 v0 = *(const float4*)s;
    float4 v1 = *(const float4*)(s + 4);
    bf16x8 w;
    w[0] = (short)f2b(v0.x); w[1] = (short)f2b(v0.y); w[2] = (short)f2b(v0.z); w[3] = (short)f2b(v0.w);
    w[4] = (short)f2b(v1.x); w[5] = (short)f2b(v1.y); w[6] = (short)f2b(v1.z); w[7] = (short)f2b(v1.w);
    *(bf16x8*)(dst + i * 8) = w;
  }
}

// ---------------- preproc: f32 [B][R][C] -> bf16 [B][C][R] ------------------
__global__ __launch_bounds__(256) void transpose_convert_kernel(
    const float* __restrict__ srcAll, unsigned short* __restrict__ dstAll,
    int R, int C) {
  const float* src = srcAll + (size_t)blockIdx.z * R * C;
  unsigned short* dst = dstAll + (size_t)blockIdx.z * R * C;
  int c0 = blockIdx.x * 64, r0 = blockIdx.y * 64;
  __shared__ float tile[64][73];
  int t = threadIdx.x;
  int sr = t >> 3;           // 0..31
  int sc = (t & 7) * 8;      // 0..56
#pragma unroll
  for (int rr = 0; rr < 2; ++rr) {
    int row = sr + rr * 32;
    const float* s = src + (size_t)(r0 + row) * C + c0 + sc;
    float4 v0 = *(const float4*)s;
    float4 v1 = *(const float4*)(s + 4);
    tile[row][sc + 0] = v0.x; tile[row][sc + 1] = v0.y;
    tile[row][sc + 2] = v0.z; tile[row][sc + 3] = v0.w;
    tile[row][sc + 4] = v1.x; tile[row][sc + 5] = v1.y;
    tile[row][sc + 6] = v1.z; tile[row][sc + 7] = v1.w;
  }
  __syncthreads();
#pragma unroll
  for (int pp = 0; pp < 2; ++pp) {
    int cc = sr + pp * 32;
    int rc = sc;
    bf16x8 w;
#pragma unroll
    for (int j = 0; j < 8; ++j) w[j] = (short)f2b(tile[rc + j][cc]);
    *(bf16x8*)(dst + (size_t)(c0 + cc) * R + r0 + rc) = w;
  }
}

// ---------------- Router ----------------------------------------------------
__global__ __launch_bounds__(64) void router_kernel(
    const float* __restrict__ h, const float* __restrict__ gate_w,
    const float* __restrict__ wsg,
    int* __restrict__ cnt, int* __restrict__ slot_e, int* __restrict__ slot_pos,
    float* __restrict__ slot_w, float* __restrict__ gout, int D) {
  int t = blockIdx.x;
  int lane = threadIdx.x;
  float acc[8] = {0.f, 0.f, 0.f, 0.f, 0.f, 0.f, 0.f, 0.f};
  float aw = 0.f;
  const float* hrow = h + (size_t)t * D;
  for (int d = lane; d < D; d += 64) {
    float hv = hrow[d];
    float4 g0 = *(const float4*)(gate_w + (size_t)d * 8);
    float4 g1 = *(const float4*)(gate_w + (size_t)d * 8 + 4);
    acc[0] += hv * g0.x; acc[1] += hv * g0.y; acc[2] += hv * g0.z; acc[3] += hv * g0.w;
    acc[4] += hv * g1.x; acc[5] += hv * g1.y; acc[6] += hv * g1.z; acc[7] += hv * g1.w;
    aw += hv * wsg[d];
  }
#pragma unroll
  for (int off = 32; off > 0; off >>= 1) {
#pragma unroll
    for (int e = 0; e < 8; ++e) acc[e] += __shfl_down(acc[e], off);
    aw += __shfl_down(aw, off);
  }
  if (lane == 0) {
    int e0 = 0; float m0v = acc[0];
#pragma unroll
    for (int e = 1; e < 8; ++e) if (acc[e] > m0v) { m0v = acc[e]; e0 = e; }
    int e1 = -1; float m1v = -3.4e38f;
#pragma unroll
    for (int e = 0; e < 8; ++e) if (e != e0 && acc[e] > m1v) { m1v = acc[e]; e1 = e; }
    if (e1 < 0) e1 = (e0 + 1) & 7;
    float r = __expf(m1v - m0v);
    float w0 = 1.f / (1.f + r);
    float w1 = 1.f - w0;
    int p;
    p = atomicAdd(&cnt[e0], 1);
    slot_e[2 * t] = e0; slot_pos[2 * t] = p; slot_w[2 * t] = w0;
    p = atomicAdd(&cnt[e1], 1);
    slot_e[2 * t + 1] = e1; slot_pos[2 * t + 1] = p; slot_w[2 * t + 1] = w1;
    gout[t] = 1.f / (1.f + __expf(-aw));
  }
}

__global__ void scan_kernel(const int* __restrict__ cnt, int* __restrict__ offs, int E) {
  if (threadIdx.x == 0 && blockIdx.x == 0) {
    int s = 0;
    for (int e = 0; e < E; ++e) { offs[e] = s; s += cnt[e]; }
    offs[E] = s;
  }
}

// fill: forward map row->token/weight AND inverse map slot->row
__global__ void fill_kernel(const int* __restrict__ slot_e, const int* __restrict__ slot_pos,
                            const float* __restrict__ slot_w, const int* __restrict__ offs,
                            int* __restrict__ rowtok, float* __restrict__ roww,
                            int* __restrict__ tokslot, int n2T, int E) {
  int i = blockIdx.x * blockDim.x + threadIdx.x;
  if (i < n2T) {
    int e = slot_e[i];
    if (e < 0) e = 0; if (e >= E) e = E - 1;
    int row = offs[e] + slot_pos[i];
    if (row < 0) row = 0; if (row >= n2T) row = n2T - 1;
    rowtok[row] = i >> 1;
    roww[row] = slot_w[i];
    tokslot[i] = row;
  }
}

// ============================================================================
// FAST PATH v5: 512-thread 256-row tiles (87 FLOP/staged-byte vs v4's 32) —
// same proven per-wave MFMA structure, 8 waves cover 256 rows.
// LDS layout [rowblock8][kgroup][row%8] (16B chunks), conflict-free ds_read_b128.
// Expert down-proj writes per-slot ye[2T][D] bf16 (NO atomics); shared down-proj
// epilogue fuses the 2-way gather combine and writes out once.
// ============================================================================
#define LDSOFF(row, kg) (((row) >> 3) * 512 + (kg) * 64 + ((row) & 7) * 8)

// ---- act: C = silu(A Bg^T) * (A Bu^T); tile 256(m) x 64(n), BK=64 ----------
template <bool EXPERT, int K>
__global__ __launch_bounds__(512) void gemm_act3_kernel(
    const unsigned short* __restrict__ hb,     // bf16 [T][K]
    const unsigned short* __restrict__ BgT,    // bf16 [(E)][N][K]
    const unsigned short* __restrict__ BuT,    // bf16 [(E)][N][K]
    unsigned short* __restrict__ actOut,       // bf16 [rows][N]
    const int* __restrict__ offs, const int* __restrict__ rowtok,
    int N, int rowsDirect, int T) {
  int e = EXPERT ? blockIdx.z : 0;
  int base = 0, cnt = rowsDirect;
  if (EXPERT) { base = offs[e]; cnt = offs[e + 1] - base; }
  int m0 = blockIdx.x * 256;
  if (m0 >= cnt) return;
  int n0 = blockIdx.y * 64;

  const unsigned short* Bg = BgT + (size_t)e * N * K;
  const unsigned short* Bu = BuT + (size_t)e * N * K;

  __shared__ __align__(16) unsigned short As[256 * 64];   // 32 KB
  __shared__ __align__(16) unsigned short Bgs[64 * 64];   // 8 KB
  __shared__ __align__(16) unsigned short Bus[64 * 64];   // 8 KB

  int tid = threadIdx.x, lane = tid & 63, wave = tid >> 6;  // 8 waves
  int r8 = lane & 7, kg = lane >> 3;
  int quad = lane >> 4, l16 = lane & 15;

  // staging: wave w stages A rows [w*32, w*32+32), B rows [w*8, w*8+8) per mat
  const unsigned short* aSrc[4];
#pragma unroll
  for (int t = 0; t < 4; ++t) {
    int gr = m0 + wave * 32 + t * 8 + r8;
    if (gr >= cnt) gr = cnt - 1;
    int tok = EXPERT ? rowtok[base + gr] : gr;
    if (tok < 0) tok = 0; if (tok >= T) tok = T - 1;
    aSrc[t] = hb + (size_t)tok * K + kg * 8;
  }
  int nB = n0 + wave * 8 + r8;
  const unsigned short* gSrc = Bg + (size_t)nB * K + kg * 8;
  const unsigned short* uSrc = Bu + (size_t)nB * K + kg * 8;
  unsigned short* aDst[4];
#pragma unroll
  for (int t = 0; t < 4; ++t) aDst[t] = As + (wave * 4 + t) * 512;
  unsigned short* gDst = Bgs + wave * 512;
  unsigned short* uDst = Bus + wave * 512;

  f32x4 accG[2][4] = {};
  f32x4 accU[2][4] = {};

  for (int kt = 0; kt < K; kt += 64) {
#pragma unroll
    for (int t = 0; t < 4; ++t) async_b128(aSrc[t] + kt, aDst[t]);
    async_b128(gSrc + kt, gDst);
    async_b128(uSrc + kt, uDst);
    __syncthreads();  // drains vmcnt (global_load_lds) + barrier
#pragma unroll
    for (int ks = 0; ks < 2; ++ks) {
      int kq = ks * 4 + quad;
      bf16x8 a[2], bg[4], bu[4];
#pragma unroll
      for (int mi = 0; mi < 2; ++mi) {
        int m = wave * 32 + mi * 16 + l16;
        a[mi] = *(const bf16x8*)(As + LDSOFF(m, kq));
      }
#pragma unroll
      for (int nj = 0; nj < 4; ++nj) {
        int n = nj * 16 + l16;
        bg[nj] = *(const bf16x8*)(Bgs + LDSOFF(n, kq));
        bu[nj] = *(const bf16x8*)(Bus + LDSOFF(n, kq));
      }
#pragma unroll
      for (int mi = 0; mi < 2; ++mi)
#pragma unroll
        for (int nj = 0; nj < 4; ++nj) {
          accG[mi][nj] = __builtin_amdgcn_mfma_f32_16x16x32_bf16(a[mi], bg[nj], accG[mi][nj], 0, 0, 0);
          accU[mi][nj] = __builtin_amdgcn_mfma_f32_16x16x32_bf16(a[mi], bu[nj], accU[mi][nj], 0, 0, 0);
        }
    }
    __syncthreads();  // protect LDS before next stage
  }

#pragma unroll
  for (int mi = 0; mi < 2; ++mi)
#pragma unroll
    for (int nj = 0; nj < 4; ++nj)
#pragma unroll
      for (int r = 0; r < 4; ++r) {
        int grow = m0 + wave * 32 + mi * 16 + quad * 4 + r;
        if (grow < cnt) {
          int col = n0 + nj * 16 + l16;
          float gv = accG[mi][nj][r], uv = accU[mi][nj][r];
          float sv = gv / (1.f + __expf(-gv)) * uv;
          actOut[(size_t)(base + grow) * N + col] = f2b(sv);
        }
      }
}

// ---- comb: down-proj; tile 256 x 128, BK=64 --------------------------------
// MODE 0: expert down-proj -> ye[2T][N] bf16 (plain coalesced stores, no atomics)
// MODE 1: shared down-proj + fused final combine:
//         out[t][c] = gsig[t]*v + w0*ye[r0][c] + w1*ye[r1][c]   (writes out once)
template <int MODE, int K>
__global__ __launch_bounds__(512) void gemm_comb3_kernel(
    const unsigned short* __restrict__ A,      // bf16 [rows][K] contiguous
    const unsigned short* __restrict__ BT,     // bf16 [(E)][N][K]
    const int* __restrict__ offs,
    const int* __restrict__ tokslot,           // [2T] slot -> compacted row
    const float* __restrict__ slot_w,          // [2T] slot weight
    const float* __restrict__ gsig,            // [T] shared sigmoid gate
    const unsigned short* __restrict__ ye_in,  // bf16 [2T][N] (MODE 1)
    unsigned short* __restrict__ ye_out,       // bf16 [2T][N] (MODE 0)
    float* __restrict__ out,                   // f32 [T][N]   (MODE 1)
    int N, int rowsDirect, int T) {
  int e = (MODE == 0) ? blockIdx.z : 0;
  int base = 0, cnt = rowsDirect;
  if (MODE == 0) { base = offs[e]; cnt = offs[e + 1] - base; }
  int m0 = blockIdx.x * 256;
  if (m0 >= cnt) return;
  int n0 = blockIdx.y * 128;

  const unsigned short* B = BT + (size_t)e * N * K;

  __shared__ __align__(16) unsigned short As[256 * 64];   // 32 KB
  __shared__ __align__(16) unsigned short Bs[128 * 64];   // 16 KB

  int tid = threadIdx.x, lane = tid & 63, wave = tid >> 6;  // 8 waves
  int r8 = lane & 7, kg = lane >> 3;
  int quad = lane >> 4, l16 = lane & 15;
  int mBase = (wave >> 1) * 64, nBase = (wave & 1) * 64;

  // staging: wave w stages A rows [w*32,w*32+32), B rows [w*16,w*16+16)
  const unsigned short* aSrc[4];
#pragma unroll
  for (int t = 0; t < 4; ++t) {
    int gr = m0 + wave * 32 + t * 8 + r8;
    if (gr >= cnt) gr = cnt - 1;
    aSrc[t] = A + (size_t)(base + gr) * K + kg * 8;
  }
  const unsigned short* bSrc[2];
#pragma unroll
  for (int t = 0; t < 2; ++t) {
    int n = n0 + wave * 16 + t * 8 + r8;
    bSrc[t] = B + (size_t)n * K + kg * 8;
  }
  unsigned short* aDst[4];
#pragma unroll
  for (int t = 0; t < 4; ++t) aDst[t] = As + (wave * 4 + t) * 512;
  unsigned short* bDst[2];
#pragma unroll
  for (int t = 0; t < 2; ++t) bDst[t] = Bs + (wave * 2 + t) * 512;

  f32x4 acc[4][4] = {};

  for (int kt = 0; kt < K; kt += 64) {
#pragma unroll
    for (int t = 0; t < 4; ++t) async_b128(aSrc[t] + kt, aDst[t]);
#pragma unroll
    for (int t = 0; t < 2; ++t) async_b128(bSrc[t] + kt, bDst[t]);
    __syncthreads();
#pragma unroll
    for (int ks = 0; ks < 2; ++ks) {
      int kq = ks * 4 + quad;
      bf16x8 a[4], b[4];
#pragma unroll
      for (int mi = 0; mi < 4; ++mi) {
        int m = mBase + mi * 16 + l16;
        a[mi] = *(const bf16x8*)(As + LDSOFF(m, kq));
      }
#pragma unroll
      for (int nj = 0; nj < 4; ++nj) {
        int n = nBase + nj * 16 + l16;
        b[nj] = *(const bf16x8*)(Bs + LDSOFF(n, kq));
      }
#pragma unroll
      for (int mi = 0; mi < 4; ++mi)
#pragma unroll
        for (int nj = 0; nj < 4; ++nj)
          acc[mi][nj] = __builtin_amdgcn_mfma_f32_16x16x32_bf16(a[mi], b[nj], acc[mi][nj], 0, 0, 0);
    }
    __syncthreads();
  }

#pragma unroll
  for (int mi = 0; mi < 4; ++mi)
#pragma unroll
    for (int r = 0; r < 4; ++r) {
      int grow = m0 + mBase + mi * 16 + quad * 4 + r;
      if (grow < cnt) {
        if (MODE == 0) {
#pragma unroll
          for (int nj = 0; nj < 4; ++nj) {
            int col = n0 + nBase + nj * 16 + l16;
            ye_out[(size_t)(base + grow) * N + col] = f2b(acc[mi][nj][r]);
          }
        } else {
          int r0 = tokslot[2 * grow], r1 = tokslot[2 * grow + 1];
          float w0 = slot_w[2 * grow], w1 = slot_w[2 * grow + 1];
          float gv = gsig[grow];
#pragma unroll
          for (int nj = 0; nj < 4; ++nj) {
            int col = n0 + nBase + nj * 16 + l16;
            float v = acc[mi][nj][r];
            float e0 = b2f(ye_in[(size_t)r0 * N + col]);
            float e1 = b2f(ye_in[(size_t)r1 * N + col]);
            out[(size_t)grow * N + col] = gv * v + w0 * e0 + w1 * e1;
          }
        }
      }
    }
}

// ============================================================================
// FALLBACK PATH (round-3 proven): f32-staging LDS GEMMs + token chunking.
// ============================================================================
template <bool EXPERT>
__global__ __launch_bounds__(256) void gemm_act_f32_kernel(
    const float* __restrict__ X, const float* __restrict__ BgAll,
    const float* __restrict__ BuAll, unsigned short* __restrict__ actOut,
    const int* __restrict__ offs, const int* __restrict__ rowtok,
    int K, int N, int rowsDirect, int maxTok) {
  int e = EXPERT ? blockIdx.z : 0;
  int base = 0, cnt = rowsDirect;
  if (EXPERT) { base = offs[e]; cnt = offs[e + 1] - base; }
  int m0 = blockIdx.y * 64;
  if (m0 >= cnt) return;
  int n0 = blockIdx.x * 64;
  const float* Bg = BgAll + (size_t)e * K * N;
  const float* Bu = BuAll + (size_t)e * K * N;
  __shared__ __align__(16) short As[64][72];
  __shared__ __align__(16) short Bgs[64][72];
  __shared__ __align__(16) short Bus[64][72];
  int tid = threadIdx.x, lane = tid & 63, wave = tid >> 6;
  int quad = lane >> 4, l16 = lane & 15;
  int mBase = (wave >> 1) * 32, nBase = (wave & 1) * 32;
  f32x4 accG[2][2] = {};
  f32x4 accU[2][2] = {};
  int sr = tid >> 3, sc = (tid & 7) * 8;
  size_t aRowOff[2];
#pragma unroll
  for (int rr = 0; rr < 2; ++rr) {
    int gr = m0 + sr + rr * 32;
    if (gr >= cnt) gr = cnt - 1;
    int tokenRow = EXPERT ? rowtok[base + gr] : gr;
    if (tokenRow < 0) tokenRow = 0;
    if (tokenRow >= maxTok) tokenRow = maxTok - 1;
    aRowOff[rr] = (size_t)tokenRow * K;
  }
  for (int kt = 0; kt < K; kt += 64) {
#pragma unroll
    for (int rr = 0; rr < 2; ++rr) {
      int r = sr + rr * 32;
      const float* src = X + aRowOff[rr] + kt + sc;
      float4 v0 = *(const float4*)src;
      float4 v1 = *(const float4*)(src + 4);
      bf16x8 w;
      w[0] = (short)f2b(v0.x); w[1] = (short)f2b(v0.y); w[2] = (short)f2b(v0.z); w[3] = (short)f2b(v0.w);
      w[4] = (short)f2b(v1.x); w[5] = (short)f2b(v1.y); w[6] = (short)f2b(v1.z); w[7] = (short)f2b(v1.w);
      *(bf16x8*)&As[r][sc] = w;
    }
#pragma unroll
    for (int rr = 0; rr < 2; ++rr) {
      int kk = sr + rr * 32;
      const float* bg = Bg + (size_t)(kt + kk) * N + n0 + sc;
      const float* bu = Bu + (size_t)(kt + kk) * N + n0 + sc;
      float4 g0 = *(const float4*)bg; float4 g1 = *(const float4*)(bg + 4);
      float4 u0 = *(const float4*)bu; float4 u1 = *(const float4*)(bu + 4);
      Bgs[sc + 0][kk] = (short)f2b(g0.x); Bgs[sc + 1][kk] = (short)f2b(g0.y);
      Bgs[sc + 2][kk] = (short)f2b(g0.z); Bgs[sc + 3][kk] = (short)f2b(g0.w);
      Bgs[sc + 4][kk] = (short)f2b(g1.x); Bgs[sc + 5][kk] = (short)f2b(g1.y);
      Bgs[sc + 6][kk] = (short)f2b(g1.z); Bgs[sc + 7][kk] = (short)f2b(g1.w);
      Bus[sc + 0][kk] = (short)f2b(u0.x); Bus[sc + 1][kk] = (short)f2b(u0.y);
      Bus[sc + 2][kk] = (short)f2b(u0.z); Bus[sc + 3][kk] = (short)f2b(u0.w);
      Bus[sc + 4][kk] = (short)f2b(u1.x); Bus[sc + 5][kk] = (short)f2b(u1.y);
      Bus[sc + 6][kk] = (short)f2b(u1.z); Bus[sc + 7][kk] = (short)f2b(u1.w);
    }
    __syncthreads();
#pragma unroll
    for (int ks = 0; ks < 2; ++ks) {
      bf16x8 a[2], bg[2], bu[2];
#pragma unroll
      for (int i = 0; i < 2; ++i)
        a[i] = *(const bf16x8*)&As[mBase + i * 16 + l16][ks * 32 + quad * 8];
#pragma unroll
      for (int i = 0; i < 2; ++i) {
        bg[i] = *(const bf16x8*)&Bgs[nBase + i * 16 + l16][ks * 32 + quad * 8];
        bu[i] = *(const bf16x8*)&Bus[nBase + i * 16 + l16][ks * 32 + quad * 8];
      }
#pragma unroll
      for (int i = 0; i < 2; ++i)
#pragma unroll
        for (int j = 0; j < 2; ++j) {
          accG[i][j] = __builtin_amdgcn_mfma_f32_16x16x32_bf16(a[i], bg[j], accG[i][j], 0, 0, 0);
          accU[i][j] = __builtin_amdgcn_mfma_f32_16x16x32_bf16(a[i], bu[j], accU[i][j], 0, 0, 0);
        }
    }
    __syncthreads();
  }
#pragma unroll
  for (int i = 0; i < 2; ++i)
#pragma unroll
    for (int j = 0; j < 2; ++j)
#pragma unroll
      for (int r = 0; r < 4; ++r) {
        int row = mBase + i * 16 + quad * 4 + r;
        int grow = m0 + row;
        if (grow < cnt) {
          int col = n0 + nBase + j * 16 + l16;
          float gv = accG[i][j][r], uv = accU[i][j][r];
          float sv = gv / (1.f + __expf(-gv)) * uv;
          actOut[(size_t)(base + grow) * N + col] = f2b(sv);
        }
      }
}

template <int MODE>
__global__ __launch_bounds__(256) void gemm_comb_f32_kernel(
    const unsigned short* __restrict__ A, const float* __restrict__ BAll,
    const int* __restrict__ offs, const int* __restrict__ rowtok,
    const float* __restrict__ roww, float* __restrict__ accum,
    const float* __restrict__ gsig, float* __restrict__ out,
    int K, int N, int rowsDirect, int maxTok) {
  int e = (MODE == 0) ? blockIdx.z : 0;
  int base = 0, cnt = rowsDirect;
  if (MODE == 0) { base = offs[e]; cnt = offs[e + 1] - base; }
  int m0 = blockIdx.y * 64;
  if (m0 >= cnt) return;
  int n0 = blockIdx.x * 64;
  const float* B = BAll + (size_t)e * K * N;
  __shared__ __align__(16) short As[64][72];
  __shared__ __align__(16) short Bs[64][72];
  int tid = threadIdx.x, lane = tid & 63, wave = tid >> 6;
  int quad = lane >> 4, l16 = lane & 15;
  int mBase = (wave >> 1) * 32, nBase = (wave & 1) * 32;
  f32x4 acc[2][2] = {};
  int sr = tid >> 3, sc = (tid & 7) * 8;
  size_t aRowOff[2];
#pragma unroll
  for (int rr = 0; rr < 2; ++rr) {
    int gr = m0 + sr + rr * 32;
    if (gr >= cnt) gr = cnt - 1;
    aRowOff[rr] = (size_t)(base + gr) * K;
  }
  for (int kt = 0; kt < K; kt += 64) {
#pragma unroll
    for (int rr = 0; rr < 2; ++rr) {
      int r = sr + rr * 32;
      *(bf16x8*)&As[r][sc] = *(const bf16x8*)(A + aRowOff[rr] + kt + sc);
    }
#pragma unroll
    for (int rr = 0; rr < 2; ++rr) {
      int kk = sr + rr * 32;
      const float* bp = B + (size_t)(kt + kk) * N + n0 + sc;
      float4 b0 = *(const float4*)bp; float4 b1 = *(const float4*)(bp + 4);
      Bs[sc + 0][kk] = (short)f2b(b0.x); Bs[sc + 1][kk] = (short)f2b(b0.y);
      Bs[sc + 2][kk] = (short)f2b(b0.z); Bs[sc + 3][kk] = (short)f2b(b0.w);
      Bs[sc + 4][kk] = (short)f2b(b1.x); Bs[sc + 5][kk] = (short)f2b(b1.y);
      Bs[sc + 6][kk] = (short)f2b(b1.z); Bs[sc + 7][kk] = (short)f2b(b1.w);
    }
    __syncthreads();
#pragma unroll
    for (int ks = 0; ks < 2; ++ks) {
      bf16x8 a[2], b[2];
#pragma unroll
      for (int i = 0; i < 2; ++i)
        a[i] = *(const bf16x8*)&As[mBase + i * 16 + l16][ks * 32 + quad * 8];
#pragma unroll
      for (int i = 0; i < 2; ++i)
        b[i] = *(const bf16x8*)&Bs[nBase + i * 16 + l16][ks * 32 + quad * 8];
#pragma unroll
      for (int i = 0; i < 2; ++i)
#pragma unroll
        for (int j = 0; j < 2; ++j)
          acc[i][j] = __builtin_amdgcn_mfma_f32_16x16x32_bf16(a[i], b[j], acc[i][j], 0, 0, 0);
    }
    __syncthreads();
  }
#pragma unroll
  for (int i = 0; i < 2; ++i)
#pragma unroll
    for (int j = 0; j < 2; ++j)
#pragma unroll
      for (int r = 0; r < 4; ++r) {
        int row = mBase + i * 16 + quad * 4 + r;
        int grow = m0 + row;
        if (grow < cnt) {
          int col = n0 + nBase + j * 16 + l16;
          float v = acc[i][j][r];
          if (MODE == 0) {
            int tok = rowtok[base + grow];
            if (tok < 0) tok = 0;
            if (tok >= maxTok) tok = maxTok - 1;
            atomicAdd(&accum[(size_t)tok * N + col], roww[base + grow] * v);
          } else {
            out[(size_t)grow * N + col] = accum[(size_t)grow * N + col] + gsig[grow] * v;
          }
        }
      }
}

// ---------------------------------------------------------------------------
extern "C" void kernel_launch(void* const* d_in, const int* in_sizes, int n_in,
                              void* d_out, int out_size, void* d_ws, size_t ws_size,
                              hipStream_t stream) {
  const float* h       = (const float*)d_in[0];
  const float* gate_w  = (const float*)d_in[1];
  const float* w_gate  = (const float*)d_in[2];
  const float* w_up    = (const float*)d_in[3];
  const float* w_down  = (const float*)d_in[4];
  const float* ws_gate = (const float*)d_in[5];
  const float* ws_up   = (const float*)d_in[6];
  const float* ws_down = (const float*)d_in[7];
  const float* wsg     = (const float*)d_in[8];
  float* out = (float*)d_out;

  const int D  = in_sizes[8];            // 2048
  const int T  = in_sizes[0] / D;        // 8192
  const int E  = in_sizes[1] / D;        // 8
  const int F  = in_sizes[2] / (E * D);  // 1024
  const int FS = in_sizes[5] / D;        // 2048
  (void)n_in; (void)out_size;

  const int actPerTok = (2 * F > FS ? 2 * F : FS);

  size_t al = 256;
  auto rnd = [&](size_t b) { return (b + al - 1) & ~(al - 1); };
  size_t need = 0;
  need += rnd((size_t)T * D * 2);            // hb
  need += rnd((size_t)E * D * F * 2) * 3;    // wgT, wuT, wdT
  need += rnd((size_t)D * FS * 2) * 3;       // wsgT, wsuT, wsdT
  need += rnd((size_t)T * actPerTok * 2);    // act
  need += rnd((size_t)T * 4);                // g
  need += rnd((size_t)E * 4) + rnd((size_t)(E + 1) * 4);
  need += rnd((size_t)2 * T * 4) * 6;        // slot_e/pos/w, rowtok, roww, tokslot

  bool shapeOK = (D == 2048 && F == 1024 && FS == 2048 && E == 8 && (T % 256) == 0);

  if (shapeOK && ws_size >= need) {
    // ================= FAST PATH v5 =================
    char* ws = (char*)d_ws;
    size_t off = 0;
    auto alloc = [&](size_t bytes) -> void* { void* p = ws + off; off += rnd(bytes); return p; };
    unsigned short* hb   = (unsigned short*)alloc((size_t)T * D * 2);
    unsigned short* wgT  = (unsigned short*)alloc((size_t)E * D * F * 2);
    unsigned short* wuT  = (unsigned short*)alloc((size_t)E * D * F * 2);
    unsigned short* wdT  = (unsigned short*)alloc((size_t)E * D * F * 2);
    unsigned short* wsgT = (unsigned short*)alloc((size_t)D * FS * 2);
    unsigned short* wsuT = (unsigned short*)alloc((size_t)D * FS * 2);
    unsigned short* wsdT = (unsigned short*)alloc((size_t)D * FS * 2);
    unsigned short* act  = (unsigned short*)alloc((size_t)T * actPerTok * 2);
    float* g      = (float*)alloc((size_t)T * 4);
    int* cnt      = (int*)alloc((size_t)E * 4);
    int* offs     = (int*)alloc((size_t)(E + 1) * 4);
    int* slot_e   = (int*)alloc((size_t)2 * T * 4);
    int* slot_pos = (int*)alloc((size_t)2 * T * 4);
    float* slot_w = (float*)alloc((size_t)2 * T * 4);
    int* rowtok   = (int*)alloc((size_t)2 * T * 4);
    float* roww   = (float*)alloc((size_t)2 * T * 4);
    int* tokslot  = (int*)alloc((size_t)2 * T * 4);

    // ye[2T][D] bf16 aliases wgT+wuT: 2*T*D shorts == 2*(E*D*F) shorts, and
    // wgT/wuT are dead after gemm_act3<true> completes (stream-ordered).
    unsigned short* ye = wgT;

    zero_i32_kernel<<<1, 64, 0, stream>>>(cnt, E);

    convert_bf16_kernel<<<2048, 256, 0, stream>>>(h, hb, (long)T * D / 8);
    transpose_convert_kernel<<<dim3(F / 64, D / 64, E), 256, 0, stream>>>(w_gate, wgT, D, F);
    transpose_convert_kernel<<<dim3(F / 64, D / 64, E), 256, 0, stream>>>(w_up, wuT, D, F);
    transpose_convert_kernel<<<dim3(D / 64, F / 64, E), 256, 0, stream>>>(w_down, wdT, F, D);
    transpose_convert_kernel<<<dim3(FS / 64, D / 64, 1), 256, 0, stream>>>(ws_gate, wsgT, D, FS);
    transpose_convert_kernel<<<dim3(FS / 64, D / 64, 1), 256, 0, stream>>>(ws_up, wsuT, D, FS);
    transpose_convert_kernel<<<dim3(D / 64, FS / 64, 1), 256, 0, stream>>>(ws_down, wsdT, FS, D);

    router_kernel<<<T, 64, 0, stream>>>(h, gate_w, wsg, cnt, slot_e, slot_pos, slot_w, g, D);
    scan_kernel<<<1, 64, 0, stream>>>(cnt, offs, E);
    fill_kernel<<<(2 * T + 255) / 256, 256, 0, stream>>>(slot_e, slot_pos, slot_w, offs,
                                                         rowtok, roww, tokslot, 2 * T, E);

    int gxE = (2 * T) / 256;  // 64: covers worst-case per-expert cnt (= 2T)
    int gxS = T / 256;        // 32
    // Expert gate/up + silu*mul -> act[2T, F]
    gemm_act3_kernel<true, 2048><<<dim3(gxE, F / 64, E), 512, 0, stream>>>(
        hb, wgT, wuT, act, offs, rowtok, F, 0, T);
    // Expert down-proj -> ye[2T, D] bf16 (no atomics; overwrites wgT/wuT)
    gemm_comb3_kernel<0, 1024><<<dim3(gxE, D / 128, E), 512, 0, stream>>>(
        act, wdT, offs, nullptr, nullptr, nullptr, nullptr, ye, nullptr, D, 0, T);
    // Shared gate/up -> act[T, FS]
    gemm_act3_kernel<false, 2048><<<dim3(gxS, FS / 64, 1), 512, 0, stream>>>(
        hb, wsgT, wsuT, act, nullptr, nullptr, FS, T, T);
    // Shared down-proj + fused gather-combine: out = g*shared + w0*ye[r0] + w1*ye[r1]
    gemm_comb3_kernel<1, 2048><<<dim3(gxS, D / 128, 1), 512, 0, stream>>>(
        act, wsdT, nullptr, tokslot, slot_w, g, ye, nullptr, out, D, T, T);
    return;
  }

  // ================= FALLBACK PATH (round-3 proven, chunked) =================
  size_t perTok = (size_t)D * 4 + (size_t)actPerTok * 2 + 4 + 48;
  size_t avail = ws_size > 4096 ? ws_size - 4096 : 0;
  long TcL = (long)(avail / (perTok + 8));
  int Tc = (int)(TcL > T ? T : TcL);
  Tc &= ~63;
  if (Tc < 64) Tc = 64;

  for (int t0 = 0; t0 < T; t0 += Tc) {
    int Tcur = (T - t0 < Tc) ? (T - t0) : Tc;
    const float* hC = h + (size_t)t0 * D;
    float* outC = out + (size_t)t0 * D;

    char* ws = (char*)d_ws;
    size_t off = 0;
    auto alloc = [&](size_t bytes) -> void* { void* p = ws + off; off += rnd(bytes); return p; };
    float* accum = (float*)alloc((size_t)Tc * D * sizeof(float));
    unsigned short* act = (unsigned short*)alloc((size_t)Tc * actPerTok * 2);
    float* g      = (float*)alloc((size_t)Tc * 4);
    int* cnt      = (int*)alloc((size_t)E * 4);
    int* offs     = (int*)alloc((size_t)(E + 1) * 4);
    int* slot_e   = (int*)alloc((size_t)2 * Tc * 4);
    int* slot_pos = (int*)alloc((size_t)2 * Tc * 4);
    float* slot_w = (float*)alloc((size_t)2 * Tc * 4);
    int* rowtok   = (int*)alloc((size_t)2 * Tc * 4);
    float* roww   = (float*)alloc((size_t)2 * Tc * 4);
    int* tokslot  = (int*)alloc((size_t)2 * Tc * 4);

    int gy = (Tcur + 63) / 64;

    zero_i32_kernel<<<1, 64, 0, stream>>>(cnt, E);
    zero_f32_kernel<<<1024, 256, 0, stream>>>(accum, (long)Tcur * D);

    router_kernel<<<Tcur, 64, 0, stream>>>(hC, gate_w, wsg, cnt, slot_e, slot_pos, slot_w, g, D);
    scan_kernel<<<1, 64, 0, stream>>>(cnt, offs, E);
    fill_kernel<<<(2 * Tcur + 255) / 256, 256, 0, stream>>>(slot_e, slot_pos, slot_w, offs,
                                                            rowtok, roww, tokslot, 2 * Tcur, E);
    gemm_act_f32_kernel<true><<<dim3(F / 64, gy, E), 256, 0, stream>>>(
        hC, w_gate, w_up, act, offs, rowtok, D, F, 0, Tcur);
    gemm_comb_f32_kernel<0><<<dim3(D / 64, gy, E), 256, 0, stream>>>(
        act, w_down, offs, rowtok, roww, accum, nullptr, nullptr, F, D, 0, Tcur);
    gemm_act_f32_kernel<false><<<dim3(FS / 64, gy, 1), 256, 0, stream>>>(
        hC, ws_gate, ws_up, act, nullptr, nullptr, D, FS, Tcur, Tcur);
    gemm_comb_f32_kernel<1><<<dim3(D / 64, gy, 1), 256, 0, stream>>>(
        act, ws_down, nullptr, nullptr, nullptr, accum, g, outC, FS, D, Tcur, Tcur);
  }
}

// Round 3
// 1724.572 us; speedup vs baseline: 1.5681x; 1.5681x over previous
//
#include <hip/hip_runtime.h>
#include <hip/hip_bf16.h>

typedef short bf16x8 __attribute__((ext_vector_type(8)));
typedef float f32x4 __attribute__((ext_vector_type(4)));

// f32 -> bf16 round-to-nearest-even, as raw bits
__device__ __forceinline__ unsigned short f2b(float f) {
  union { float f; unsigned u; } v; v.f = f;
  unsigned r = v.u + 0x7FFF + ((v.u >> 16) & 1);
  return (unsigned short)(r >> 16);
}

// bf16 raw bits -> f32
__device__ __forceinline__ float b2f(unsigned short u) {
  union { unsigned u; float f; } v; v.u = ((unsigned)u) << 16;
  return v.f;
}

// async global->LDS, 16B per lane; LDS dest = base + lane*16 (wave-uniform base)
__device__ __forceinline__ void async_b128(const void* g, void* l) {
  __builtin_amdgcn_global_load_lds(
      (const __attribute__((address_space(1))) unsigned int*)g,
      (__attribute__((address_space(3))) unsigned int*)l, 16, 0, 0);
}

// ---------------- zero-fill helpers (no hipMemsetAsync in capture) ----------
__global__ void zero_f32_kernel(float* __restrict__ p, long n) {
  long i = (long)blockIdx.x * blockDim.x + threadIdx.x;
  long stride = (long)gridDim.x * blockDim.x;
  for (; i < n; i += stride) p[i] = 0.f;
}
__global__ void zero_i32_kernel(int* __restrict__ p, int n) {
  int i = blockIdx.x * blockDim.x + threadIdx.x;
  if (i < n) p[i] = 0;
}

// ---------------- preproc: f32 -> bf16 flat convert -------------------------
__global__ __launch_bounds__(256) void convert_bf16_kernel(
    const float* __restrict__ src, unsigned short* __restrict__ dst, long n8) {
  long i = (long)blockIdx.x * blockDim.x + threadIdx.x;
  long stride = (long)gridDim.x * blockDim.x;
  for (; i < n8; i += stride) {
    const float* s = src + i * 8;
    float4 v0 = *(const float4*)s;
    float4 v1 = *(const float4*)(s + 4);
    bf16x8 w;
    w[0] = (short)f2b(v0.x); w[1] = (short)f2b(v0.y); w[2] = (short)f2b(v0.z); w[3] = (short)f2b(v0.w);
    w[4] = (short)f2b(v1.x); w[5] = (short)f2b(v1.y); w[6] = (short)f2b(v1.z); w[7] = (short)f2b(v1.w);
    *(bf16x8*)(dst + i * 8) = w;
  }
}

// ---------------- preproc: f32 [B][R][C] -> bf16 [B][C][R] ------------------
__global__ __launch_bounds__(256) void transpose_convert_kernel(
    const float* __restrict__ srcAll, unsigned short* __restrict__ dstAll,
    int R, int C) {
  const float* src = srcAll + (size_t)blockIdx.z * R * C;
  unsigned short* dst = dstAll + (size_t)blockIdx.z * R * C;
  int c0 = blockIdx.x * 64, r0 = blockIdx.y * 64;
  __shared__ float tile[64][73];
  int t = threadIdx.x;
  int sr = t >> 3;           // 0..31
  int sc = (t & 7) * 8;      // 0..56
#pragma unroll
  for (int rr = 0; rr < 2; ++rr) {
    int row = sr + rr * 32;
    const float* s = src + (size_t)(r0 + row) * C + c0 + sc;
    float4 v0 = *(const float4*)s;
    float4 v1 = *(const float4*)(s + 4);
    tile[row][sc + 0] = v0.x; tile[row][sc + 1] = v0.y;
    tile[row][sc + 2] = v0.z; tile[row][sc + 3] = v0.w;
    tile[row][sc + 4] = v1.x; tile[row][sc + 5] = v1.y;
    tile[row][sc + 6] = v1.z; tile[row][sc + 7] = v1.w;
  }
  __syncthreads();
#pragma unroll
  for (int pp = 0; pp < 2; ++pp) {
    int cc = sr + pp * 32;
    int rc = sc;
    bf16x8 w;
#pragma unroll
    for (int j = 0; j < 8; ++j) w[j] = (short)f2b(tile[rc + j][cc]);
    *(bf16x8*)(dst + (size_t)(c0 + cc) * R + r0 + rc) = w;
  }
}

// ---------------- Router ----------------------------------------------------
__global__ __launch_bounds__(64) void router_kernel(
    const float* __restrict__ h, const float* __restrict__ gate_w,
    const float* __restrict__ wsg,
    int* __restrict__ cnt, int* __restrict__ slot_e, int* __restrict__ slot_pos,
    float* __restrict__ slot_w, float* __restrict__ gout, int D) {
  int t = blockIdx.x;
  int lane = threadIdx.x;
  float acc[8] = {0.f, 0.f, 0.f, 0.f, 0.f, 0.f, 0.f, 0.f};
  float aw = 0.f;
  const float* hrow = h + (size_t)t * D;
  for (int d = lane; d < D; d += 64) {
    float hv = hrow[d];
    float4 g0 = *(const float4*)(gate_w + (size_t)d * 8);
    float4 g1 = *(const float4*)(gate_w + (size_t)d * 8 + 4);
    acc[0] += hv * g0.x; acc[1] += hv * g0.y; acc[2] += hv * g0.z; acc[3] += hv * g0.w;
    acc[4] += hv * g1.x; acc[5] += hv * g1.y; acc[6] += hv * g1.z; acc[7] += hv * g1.w;
    aw += hv * wsg[d];
  }
#pragma unroll
  for (int off = 32; off > 0; off >>= 1) {
#pragma unroll
    for (int e = 0; e < 8; ++e) acc[e] += __shfl_down(acc[e], off);
    aw += __shfl_down(aw, off);
  }
  if (lane == 0) {
    int e0 = 0; float m0v = acc[0];
#pragma unroll
    for (int e = 1; e < 8; ++e) if (acc[e] > m0v) { m0v = acc[e]; e0 = e; }
    int e1 = -1; float m1v = -3.4e38f;
#pragma unroll
    for (int e = 0; e < 8; ++e) if (e != e0 && acc[e] > m1v) { m1v = acc[e]; e1 = e; }
    if (e1 < 0) e1 = (e0 + 1) & 7;
    float r = __expf(m1v - m0v);
    float w0 = 1.f / (1.f + r);
    float w1 = 1.f - w0;
    int p;
    p = atomicAdd(&cnt[e0], 1);
    slot_e[2 * t] = e0; slot_pos[2 * t] = p; slot_w[2 * t] = w0;
    p = atomicAdd(&cnt[e1], 1);
    slot_e[2 * t + 1] = e1; slot_pos[2 * t + 1] = p; slot_w[2 * t + 1] = w1;
    gout[t] = 1.f / (1.f + __expf(-aw));
  }
}

__global__ void scan_kernel(const int* __restrict__ cnt, int* __restrict__ offs, int E) {
  if (threadIdx.x == 0 && blockIdx.x == 0) {
    int s = 0;
    for (int e = 0; e < E; ++e) { offs[e] = s; s += cnt[e]; }
    offs[E] = s;
  }
}

// fill: forward map row->token/weight AND inverse map slot->row
__global__ void fill_kernel(const int* __restrict__ slot_e, const int* __restrict__ slot_pos,
                            const float* __restrict__ slot_w, const int* __restrict__ offs,
                            int* __restrict__ rowtok, float* __restrict__ roww,
                            int* __restrict__ tokslot, int n2T, int E) {
  int i = blockIdx.x * blockDim.x + threadIdx.x;
  if (i < n2T) {
    int e = slot_e[i];
    if (e < 0) e = 0; if (e >= E) e = E - 1;
    int row = offs[e] + slot_pos[i];
    if (row < 0) row = 0; if (row >= n2T) row = n2T - 1;
    rowtok[row] = i >> 1;
    roww[row] = slot_w[i];
    tokslot[i] = row;
  }
}

// ============================================================================
// FAST PATH v6: v4 geometry (128-row tiles, 256 threads) + 2-phase
// double-buffered pipeline: STAGE(next) issued BEFORE compute(cur), ONE
// vmcnt(0)+barrier per K-step (inside __syncthreads). LDS = 64 KB/block.
// LDS layout [rowblock8][kgroup][row%8] (16B chunks), conflict-free ds_read_b128.
// Expert down-proj writes per-slot ye[2T][D] bf16 (NO atomics); shared down-proj
// epilogue fuses the 2-way gather combine and writes out once.
// ============================================================================
#define LDSOFF(row, kg) (((row) >> 3) * 512 + (kg) * 64 + ((row) & 7) * 8)

// ---- act: C = silu(A Bg^T) * (A Bu^T); tile 128(m) x 64(n), BK=64 ----------
template <bool EXPERT, int K>
__global__ __launch_bounds__(256) void gemm_act3_kernel(
    const unsigned short* __restrict__ hb,     // bf16 [T][K]
    const unsigned short* __restrict__ BgT,    // bf16 [(E)][N][K]
    const unsigned short* __restrict__ BuT,    // bf16 [(E)][N][K]
    unsigned short* __restrict__ actOut,       // bf16 [rows][N]
    const int* __restrict__ offs, const int* __restrict__ rowtok,
    int N, int rowsDirect, int T) {
  int e = EXPERT ? blockIdx.z : 0;
  int base = 0, cnt = rowsDirect;
  if (EXPERT) { base = offs[e]; cnt = offs[e + 1] - base; }
  int m0 = blockIdx.x * 128;
  if (m0 >= cnt) return;
  int n0 = blockIdx.y * 64;

  const unsigned short* Bg = BgT + (size_t)e * N * K;
  const unsigned short* Bu = BuT + (size_t)e * N * K;

  __shared__ __align__(16) unsigned short As[2][128 * 64];   // 2 x 16 KB
  __shared__ __align__(16) unsigned short Bgs[2][64 * 64];   // 2 x 8 KB
  __shared__ __align__(16) unsigned short Bus[2][64 * 64];   // 2 x 8 KB -> 64 KB

  int tid = threadIdx.x, lane = tid & 63, wave = tid >> 6;
  int r8 = lane & 7, kg = lane >> 3;
  int quad = lane >> 4, l16 = lane & 15;

  // staging sources: wave w stages A rows [w*32, w*32+32), B rows [w*16, w*16+16)
  const unsigned short* aSrc[4];
#pragma unroll
  for (int t = 0; t < 4; ++t) {
    int gr = m0 + wave * 32 + t * 8 + r8;
    if (gr >= cnt) gr = cnt - 1;
    int tok = EXPERT ? rowtok[base + gr] : gr;
    if (tok < 0) tok = 0; if (tok >= T) tok = T - 1;
    aSrc[t] = hb + (size_t)tok * K + kg * 8;
  }
  const unsigned short* gSrc[2];
  const unsigned short* uSrc[2];
#pragma unroll
  for (int t = 0; t < 2; ++t) {
    int n = n0 + wave * 16 + t * 8 + r8;
    gSrc[t] = Bg + (size_t)n * K + kg * 8;
    uSrc[t] = Bu + (size_t)n * K + kg * 8;
  }

  auto stage = [&](int buf, int kt) {
#pragma unroll
    for (int t = 0; t < 4; ++t) async_b128(aSrc[t] + kt, As[buf] + (wave * 4 + t) * 512);
#pragma unroll
    for (int t = 0; t < 2; ++t) {
      async_b128(gSrc[t] + kt, Bgs[buf] + (wave * 2 + t) * 512);
      async_b128(uSrc[t] + kt, Bus[buf] + (wave * 2 + t) * 512);
    }
  };

  f32x4 accG[2][4] = {};
  f32x4 accU[2][4] = {};

  stage(0, 0);
  __syncthreads();  // vmcnt(0) drain + barrier: buf0 ready
  int cur = 0;
  for (int kt = 0; kt < K; kt += 64) {
    if (kt + 64 < K) stage(cur ^ 1, kt + 64);  // loads fly during compute
#pragma unroll
    for (int ks = 0; ks < 2; ++ks) {
      int kq = ks * 4 + quad;
      bf16x8 a[2], bg[4], bu[4];
#pragma unroll
      for (int mi = 0; mi < 2; ++mi) {
        int m = wave * 32 + mi * 16 + l16;
        a[mi] = *(const bf16x8*)(As[cur] + LDSOFF(m, kq));
      }
#pragma unroll
      for (int nj = 0; nj < 4; ++nj) {
        int n = nj * 16 + l16;
        bg[nj] = *(const bf16x8*)(Bgs[cur] + LDSOFF(n, kq));
        bu[nj] = *(const bf16x8*)(Bus[cur] + LDSOFF(n, kq));
      }
#pragma unroll
      for (int mi = 0; mi < 2; ++mi)
#pragma unroll
        for (int nj = 0; nj < 4; ++nj) {
          accG[mi][nj] = __builtin_amdgcn_mfma_f32_16x16x32_bf16(a[mi], bg[nj], accG[mi][nj], 0, 0, 0);
          accU[mi][nj] = __builtin_amdgcn_mfma_f32_16x16x32_bf16(a[mi], bu[nj], accU[mi][nj], 0, 0, 0);
        }
    }
    __syncthreads();  // drains next-buf staging (vmcnt0) + protects cur for overwrite
    cur ^= 1;
  }

#pragma unroll
  for (int mi = 0; mi < 2; ++mi)
#pragma unroll
    for (int nj = 0; nj < 4; ++nj)
#pragma unroll
      for (int r = 0; r < 4; ++r) {
        int grow = m0 + wave * 32 + mi * 16 + quad * 4 + r;
        if (grow < cnt) {
          int col = n0 + nj * 16 + l16;
          float gv = accG[mi][nj][r], uv = accU[mi][nj][r];
          float sv = gv / (1.f + __expf(-gv)) * uv;
          actOut[(size_t)(base + grow) * N + col] = f2b(sv);
        }
      }
}

// ---- comb: down-proj; tile 128 x 128, BK=64, 2-phase dbuf ------------------
// MODE 0: expert down-proj -> ye[2T][N] bf16 (plain coalesced stores, no atomics)
// MODE 1: shared down-proj + fused final combine:
//         out[t][c] = gsig[t]*v + w0*ye[r0][c] + w1*ye[r1][c]   (writes out once)
template <int MODE, int K>
__global__ __launch_bounds__(256) void gemm_comb3_kernel(
    const unsigned short* __restrict__ A,      // bf16 [rows][K] contiguous
    const unsigned short* __restrict__ BT,     // bf16 [(E)][N][K]
    const int* __restrict__ offs,
    const int* __restrict__ tokslot,           // [2T] slot -> compacted row
    const float* __restrict__ slot_w,          // [2T] slot weight
    const float* __restrict__ gsig,            // [T] shared sigmoid gate
    const unsigned short* __restrict__ ye_in,  // bf16 [2T][N] (MODE 1)
    unsigned short* __restrict__ ye_out,       // bf16 [2T][N] (MODE 0)
    float* __restrict__ out,                   // f32 [T][N]   (MODE 1)
    int N, int rowsDirect, int T) {
  int e = (MODE == 0) ? blockIdx.z : 0;
  int base = 0, cnt = rowsDirect;
  if (MODE == 0) { base = offs[e]; cnt = offs[e + 1] - base; }
  int m0 = blockIdx.x * 128;
  if (m0 >= cnt) return;
  int n0 = blockIdx.y * 128;

  const unsigned short* B = BT + (size_t)e * N * K;

  __shared__ __align__(16) unsigned short As[2][128 * 64];   // 2 x 16 KB
  __shared__ __align__(16) unsigned short Bs[2][128 * 64];   // 2 x 16 KB -> 64 KB

  int tid = threadIdx.x, lane = tid & 63, wave = tid >> 6;
  int r8 = lane & 7, kg = lane >> 3;
  int quad = lane >> 4, l16 = lane & 15;
  int mBase = (wave >> 1) * 64, nBase = (wave & 1) * 64;

  const unsigned short* aSrc[4];
  const unsigned short* bSrc[4];
#pragma unroll
  for (int t = 0; t < 4; ++t) {
    int gr = m0 + wave * 32 + t * 8 + r8;
    if (gr >= cnt) gr = cnt - 1;
    aSrc[t] = A + (size_t)(base + gr) * K + kg * 8;
    int n = n0 + wave * 32 + t * 8 + r8;
    bSrc[t] = B + (size_t)n * K + kg * 8;
  }

  auto stage = [&](int buf, int kt) {
#pragma unroll
    for (int t = 0; t < 4; ++t) {
      async_b128(aSrc[t] + kt, As[buf] + (wave * 4 + t) * 512);
      async_b128(bSrc[t] + kt, Bs[buf] + (wave * 4 + t) * 512);
    }
  };

  f32x4 acc[4][4] = {};

  stage(0, 0);
  __syncthreads();
  int cur = 0;
  for (int kt = 0; kt < K; kt += 64) {
    if (kt + 64 < K) stage(cur ^ 1, kt + 64);
#pragma unroll
    for (int ks = 0; ks < 2; ++ks) {
      int kq = ks * 4 + quad;
      bf16x8 a[4], b[4];
#pragma unroll
      for (int mi = 0; mi < 4; ++mi) {
        int m = mBase + mi * 16 + l16;
        a[mi] = *(const bf16x8*)(As[cur] + LDSOFF(m, kq));
      }
#pragma unroll
      for (int nj = 0; nj < 4; ++nj) {
        int n = nBase + nj * 16 + l16;
        b[nj] = *(const bf16x8*)(Bs[cur] + LDSOFF(n, kq));
      }
#pragma unroll
      for (int mi = 0; mi < 4; ++mi)
#pragma unroll
        for (int nj = 0; nj < 4; ++nj)
          acc[mi][nj] = __builtin_amdgcn_mfma_f32_16x16x32_bf16(a[mi], b[nj], acc[mi][nj], 0, 0, 0);
    }
    __syncthreads();
    cur ^= 1;
  }

#pragma unroll
  for (int mi = 0; mi < 4; ++mi)
#pragma unroll
    for (int r = 0; r < 4; ++r) {
      int grow = m0 + mBase + mi * 16 + quad * 4 + r;
      if (grow < cnt) {
        if (MODE == 0) {
#pragma unroll
          for (int nj = 0; nj < 4; ++nj) {
            int col = n0 + nBase + nj * 16 + l16;
            ye_out[(size_t)(base + grow) * N + col] = f2b(acc[mi][nj][r]);
          }
        } else {
          int r0 = tokslot[2 * grow], r1 = tokslot[2 * grow + 1];
          float w0 = slot_w[2 * grow], w1 = slot_w[2 * grow + 1];
          float gv = gsig[grow];
#pragma unroll
          for (int nj = 0; nj < 4; ++nj) {
            int col = n0 + nBase + nj * 16 + l16;
            float v = acc[mi][nj][r];
            float e0 = b2f(ye_in[(size_t)r0 * N + col]);
            float e1 = b2f(ye_in[(size_t)r1 * N + col]);
            out[(size_t)grow * N + col] = gv * v + w0 * e0 + w1 * e1;
          }
        }
      }
    }
}

// ============================================================================
// FALLBACK PATH (round-3 proven): f32-staging LDS GEMMs + token chunking.
// ============================================================================
template <bool EXPERT>
__global__ __launch_bounds__(256) void gemm_act_f32_kernel(
    const float* __restrict__ X, const float* __restrict__ BgAll,
    const float* __restrict__ BuAll, unsigned short* __restrict__ actOut,
    const int* __restrict__ offs, const int* __restrict__ rowtok,
    int K, int N, int rowsDirect, int maxTok) {
  int e = EXPERT ? blockIdx.z : 0;
  int base = 0, cnt = rowsDirect;
  if (EXPERT) { base = offs[e]; cnt = offs[e + 1] - base; }
  int m0 = blockIdx.y * 64;
  if (m0 >= cnt) return;
  int n0 = blockIdx.x * 64;
  const float* Bg = BgAll + (size_t)e * K * N;
  const float* Bu = BuAll + (size_t)e * K * N;
  __shared__ __align__(16) short As[64][72];
  __shared__ __align__(16) short Bgs[64][72];
  __shared__ __align__(16) short Bus[64][72];
  int tid = threadIdx.x, lane = tid & 63, wave = tid >> 6;
  int quad = lane >> 4, l16 = lane & 15;
  int mBase = (wave >> 1) * 32, nBase = (wave & 1) * 32;
  f32x4 accG[2][2] = {};
  f32x4 accU[2][2] = {};
  int sr = tid >> 3, sc = (tid & 7) * 8;
  size_t aRowOff[2];
#pragma unroll
  for (int rr = 0; rr < 2; ++rr) {
    int gr = m0 + sr + rr * 32;
    if (gr >= cnt) gr = cnt - 1;
    int tokenRow = EXPERT ? rowtok[base + gr] : gr;
    if (tokenRow < 0) tokenRow = 0;
    if (tokenRow >= maxTok) tokenRow = maxTok - 1;
    aRowOff[rr] = (size_t)tokenRow * K;
  }
  for (int kt = 0; kt < K; kt += 64) {
#pragma unroll
    for (int rr = 0; rr < 2; ++rr) {
      int r = sr + rr * 32;
      const float* src = X + aRowOff[rr] + kt + sc;
      float4 v0 = *(const float4*)src;
      float4 v1 = *(const float4*)(src + 4);
      bf16x8 w;
      w[0] = (short)f2b(v0.x); w[1] = (short)f2b(v0.y); w[2] = (short)f2b(v0.z); w[3] = (short)f2b(v0.w);
      w[4] = (short)f2b(v1.x); w[5] = (short)f2b(v1.y); w[6] = (short)f2b(v1.z); w[7] = (short)f2b(v1.w);
      *(bf16x8*)&As[r][sc] = w;
    }
#pragma unroll
    for (int rr = 0; rr < 2; ++rr) {
      int kk = sr + rr * 32;
      const float* bg = Bg + (size_t)(kt + kk) * N + n0 + sc;
      const float* bu = Bu + (size_t)(kt + kk) * N + n0 + sc;
      float4 g0 = *(const float4*)bg; float4 g1 = *(const float4*)(bg + 4);
      float4 u0 = *(const float4*)bu; float4 u1 = *(const float4*)(bu + 4);
      Bgs[sc + 0][kk] = (short)f2b(g0.x); Bgs[sc + 1][kk] = (short)f2b(g0.y);
      Bgs[sc + 2][kk] = (short)f2b(g0.z); Bgs[sc + 3][kk] = (short)f2b(g0.w);
      Bgs[sc + 4][kk] = (short)f2b(g1.x); Bgs[sc + 5][kk] = (short)f2b(g1.y);
      Bgs[sc + 6][kk] = (short)f2b(g1.z); Bgs[sc + 7][kk] = (short)f2b(g1.w);
      Bus[sc + 0][kk] = (short)f2b(u0.x); Bus[sc + 1][kk] = (short)f2b(u0.y);
      Bus[sc + 2][kk] = (short)f2b(u0.z); Bus[sc + 3][kk] = (short)f2b(u0.w);
      Bus[sc + 4][kk] = (short)f2b(u1.x); Bus[sc + 5][kk] = (short)f2b(u1.y);
      Bus[sc + 6][kk] = (short)f2b(u1.z); Bus[sc + 7][kk] = (short)f2b(u1.w);
    }
    __syncthreads();
#pragma unroll
    for (int ks = 0; ks < 2; ++ks) {
      bf16x8 a[2], bg[2], bu[2];
#pragma unroll
      for (int i = 0; i < 2; ++i)
        a[i] = *(const bf16x8*)&As[mBase + i * 16 + l16][ks * 32 + quad * 8];
#pragma unroll
      for (int i = 0; i < 2; ++i) {
        bg[i] = *(const bf16x8*)&Bgs[nBase + i * 16 + l16][ks * 32 + quad * 8];
        bu[i] = *(const bf16x8*)&Bus[nBase + i * 16 + l16][ks * 32 + quad * 8];
      }
#pragma unroll
      for (int i = 0; i < 2; ++i)
#pragma unroll
        for (int j = 0; j < 2; ++j) {
          accG[i][j] = __builtin_amdgcn_mfma_f32_16x16x32_bf16(a[i], bg[j], accG[i][j], 0, 0, 0);
          accU[i][j] = __builtin_amdgcn_mfma_f32_16x16x32_bf16(a[i], bu[j], accU[i][j], 0, 0, 0);
        }
    }
    __syncthreads();
  }
#pragma unroll
  for (int i = 0; i < 2; ++i)
#pragma unroll
    for (int j = 0; j < 2; ++j)
#pragma unroll
      for (int r = 0; r < 4; ++r) {
        int row = mBase + i * 16 + quad * 4 + r;
        int grow = m0 + row;
        if (grow < cnt) {
          int col = n0 + nBase + j * 16 + l16;
          float gv = accG[i][j][r], uv = accU[i][j][r];
          float sv = gv / (1.f + __expf(-gv)) * uv;
          actOut[(size_t)(base + grow) * N + col] = f2b(sv);
        }
      }
}

template <int MODE>
__global__ __launch_bounds__(256) void gemm_comb_f32_kernel(
    const unsigned short* __restrict__ A, const float* __restrict__ BAll,
    const int* __restrict__ offs, const int* __restrict__ rowtok,
    const float* __restrict__ roww, float* __restrict__ accum,
    const float* __restrict__ gsig, float* __restrict__ out,
    int K, int N, int rowsDirect, int maxTok) {
  int e = (MODE == 0) ? blockIdx.z : 0;
  int base = 0, cnt = rowsDirect;
  if (MODE == 0) { base = offs[e]; cnt = offs[e + 1] - base; }
  int m0 = blockIdx.y * 64;
  if (m0 >= cnt) return;
  int n0 = blockIdx.x * 64;
  const float* B = BAll + (size_t)e * K * N;
  __shared__ __align__(16) short As[64][72];
  __shared__ __align__(16) short Bs[64][72];
  int tid = threadIdx.x, lane = tid & 63, wave = tid >> 6;
  int quad = lane >> 4, l16 = lane & 15;
  int mBase = (wave >> 1) * 32, nBase = (wave & 1) * 32;
  f32x4 acc[2][2] = {};
  int sr = tid >> 3, sc = (tid & 7) * 8;
  size_t aRowOff[2];
#pragma unroll
  for (int rr = 0; rr < 2; ++rr) {
    int gr = m0 + sr + rr * 32;
    if (gr >= cnt) gr = cnt - 1;
    aRowOff[rr] = (size_t)(base + gr) * K;
  }
  for (int kt = 0; kt < K; kt += 64) {
#pragma unroll
    for (int rr = 0; rr < 2; ++rr) {
      int r = sr + rr * 32;
      *(bf16x8*)&As[r][sc] = *(const bf16x8*)(A + aRowOff[rr] + kt + sc);
    }
#pragma unroll
    for (int rr = 0; rr < 2; ++rr) {
      int kk = sr + rr * 32;
      const float* bp = B + (size_t)(kt + kk) * N + n0 + sc;
      float4 b0 = *(const float4*)bp; float4 b1 = *(const float4*)(bp + 4);
      Bs[sc + 0][kk] = (short)f2b(b0.x); Bs[sc + 1][kk] = (short)f2b(b0.y);
      Bs[sc + 2][kk] = (short)f2b(b0.z); Bs[sc + 3][kk] = (short)f2b(b0.w);
      Bs[sc + 4][kk] = (short)f2b(b1.x); Bs[sc + 5][kk] = (short)f2b(b1.y);
      Bs[sc + 6][kk] = (short)f2b(b1.z); Bs[sc + 7][kk] = (short)f2b(b1.w);
    }
    __syncthreads();
#pragma unroll
    for (int ks = 0; ks < 2; ++ks) {
      bf16x8 a[2], b[2];
#pragma unroll
      for (int i = 0; i < 2; ++i)
        a[i] = *(const bf16x8*)&As[mBase + i * 16 + l16][ks * 32 + quad * 8];
#pragma unroll
      for (int i = 0; i < 2; ++i)
        b[i] = *(const bf16x8*)&Bs[nBase + i * 16 + l16][ks * 32 + quad * 8];
#pragma unroll
      for (int i = 0; i < 2; ++i)
#pragma unroll
        for (int j = 0; j < 2; ++j)
          acc[i][j] = __builtin_amdgcn_mfma_f32_16x16x32_bf16(a[i], b[j], acc[i][j], 0, 0, 0);
    }
    __syncthreads();
  }
#pragma unroll
  for (int i = 0; i < 2; ++i)
#pragma unroll
    for (int j = 0; j < 2; ++j)
#pragma unroll
      for (int r = 0; r < 4; ++r) {
        int row = mBase + i * 16 + quad * 4 + r;
        int grow = m0 + row;
        if (grow < cnt) {
          int col = n0 + nBase + j * 16 + l16;
          float v = acc[i][j][r];
          if (MODE == 0) {
            int tok = rowtok[base + grow];
            if (tok < 0) tok = 0;
            if (tok >= maxTok) tok = maxTok - 1;
            atomicAdd(&accum[(size_t)tok * N + col], roww[base + grow] * v);
          } else {
            out[(size_t)grow * N + col] = accum[(size_t)grow * N + col] + gsig[grow] * v;
          }
        }
      }
}

// ---------------------------------------------------------------------------
extern "C" void kernel_launch(void* const* d_in, const int* in_sizes, int n_in,
                              void* d_out, int out_size, void* d_ws, size_t ws_size,
                              hipStream_t stream) {
  const float* h       = (const float*)d_in[0];
  const float* gate_w  = (const float*)d_in[1];
  const float* w_gate  = (const float*)d_in[2];
  const float* w_up    = (const float*)d_in[3];
  const float* w_down  = (const float*)d_in[4];
  const float* ws_gate = (const float*)d_in[5];
  const float* ws_up   = (const float*)d_in[6];
  const float* ws_down = (const float*)d_in[7];
  const float* wsg     = (const float*)d_in[8];
  float* out = (float*)d_out;

  const int D  = in_sizes[8];            // 2048
  const int T  = in_sizes[0] / D;        // 8192
  const int E  = in_sizes[1] / D;        // 8
  const int F  = in_sizes[2] / (E * D);  // 1024
  const int FS = in_sizes[5] / D;        // 2048
  (void)n_in; (void)out_size;

  const int actPerTok = (2 * F > FS ? 2 * F : FS);

  size_t al = 256;
  auto rnd = [&](size_t b) { return (b + al - 1) & ~(al - 1); };
  size_t need = 0;
  need += rnd((size_t)T * D * 2);            // hb
  need += rnd((size_t)E * D * F * 2) * 3;    // wgT, wuT, wdT
  need += rnd((size_t)D * FS * 2) * 3;       // wsgT, wsuT, wsdT
  need += rnd((size_t)T * actPerTok * 2);    // act
  need += rnd((size_t)T * 4);                // g
  need += rnd((size_t)E * 4) + rnd((size_t)(E + 1) * 4);
  need += rnd((size_t)2 * T * 4) * 6;        // slot_e/pos/w, rowtok, roww, tokslot

  bool shapeOK = (D == 2048 && F == 1024 && FS == 2048 && E == 8 && (T % 128) == 0);

  if (shapeOK && ws_size >= need) {
    // ================= FAST PATH v6 =================
    char* ws = (char*)d_ws;
    size_t off = 0;
    auto alloc = [&](size_t bytes) -> void* { void* p = ws + off; off += rnd(bytes); return p; };
    unsigned short* hb   = (unsigned short*)alloc((size_t)T * D * 2);
    unsigned short* wgT  = (unsigned short*)alloc((size_t)E * D * F * 2);
    unsigned short* wuT  = (unsigned short*)alloc((size_t)E * D * F * 2);
    unsigned short* wdT  = (unsigned short*)alloc((size_t)E * D * F * 2);
    unsigned short* wsgT = (unsigned short*)alloc((size_t)D * FS * 2);
    unsigned short* wsuT = (unsigned short*)alloc((size_t)D * FS * 2);
    unsigned short* wsdT = (unsigned short*)alloc((size_t)D * FS * 2);
    unsigned short* act  = (unsigned short*)alloc((size_t)T * actPerTok * 2);
    float* g      = (float*)alloc((size_t)T * 4);
    int* cnt      = (int*)alloc((size_t)E * 4);
    int* offs     = (int*)alloc((size_t)(E + 1) * 4);
    int* slot_e   = (int*)alloc((size_t)2 * T * 4);
    int* slot_pos = (int*)alloc((size_t)2 * T * 4);
    float* slot_w = (float*)alloc((size_t)2 * T * 4);
    int* rowtok   = (int*)alloc((size_t)2 * T * 4);
    float* roww   = (float*)alloc((size_t)2 * T * 4);
    int* tokslot  = (int*)alloc((size_t)2 * T * 4);

    // ye[2T][D] bf16 aliases wgT+wuT: 2*T*D shorts == 2*(E*D*F) shorts, and
    // wgT/wuT are dead after gemm_act3<true> completes (stream-ordered).
    unsigned short* ye = wgT;

    zero_i32_kernel<<<1, 64, 0, stream>>>(cnt, E);

    convert_bf16_kernel<<<2048, 256, 0, stream>>>(h, hb, (long)T * D / 8);
    transpose_convert_kernel<<<dim3(F / 64, D / 64, E), 256, 0, stream>>>(w_gate, wgT, D, F);
    transpose_convert_kernel<<<dim3(F / 64, D / 64, E), 256, 0, stream>>>(w_up, wuT, D, F);
    transpose_convert_kernel<<<dim3(D / 64, F / 64, E), 256, 0, stream>>>(w_down, wdT, F, D);
    transpose_convert_kernel<<<dim3(FS / 64, D / 64, 1), 256, 0, stream>>>(ws_gate, wsgT, D, FS);
    transpose_convert_kernel<<<dim3(FS / 64, D / 64, 1), 256, 0, stream>>>(ws_up, wsuT, D, FS);
    transpose_convert_kernel<<<dim3(D / 64, FS / 64, 1), 256, 0, stream>>>(ws_down, wsdT, FS, D);

    router_kernel<<<T, 64, 0, stream>>>(h, gate_w, wsg, cnt, slot_e, slot_pos, slot_w, g, D);
    scan_kernel<<<1, 64, 0, stream>>>(cnt, offs, E);
    fill_kernel<<<(2 * T + 255) / 256, 256, 0, stream>>>(slot_e, slot_pos, slot_w, offs,
                                                         rowtok, roww, tokslot, 2 * T, E);

    int gxE = (2 * T) / 128;  // 128: covers worst-case per-expert cnt (= 2T)
    int gxS = T / 128;        // 64
    // Expert gate/up + silu*mul -> act[2T, F]
    gemm_act3_kernel<true, 2048><<<dim3(gxE, F / 64, E), 256, 0, stream>>>(
        hb, wgT, wuT, act, offs, rowtok, F, 0, T);
    // Expert down-proj -> ye[2T, D] bf16 (no atomics; overwrites wgT/wuT)
    gemm_comb3_kernel<0, 1024><<<dim3(gxE, D / 128, E), 256, 0, stream>>>(
        act, wdT, offs, nullptr, nullptr, nullptr, nullptr, ye, nullptr, D, 0, T);
    // Shared gate/up -> act[T, FS]
    gemm_act3_kernel<false, 2048><<<dim3(gxS, FS / 64, 1), 256, 0, stream>>>(
        hb, wsgT, wsuT, act, nullptr, nullptr, FS, T, T);
    // Shared down-proj + fused gather-combine: out = g*shared + w0*ye[r0] + w1*ye[r1]
    gemm_comb3_kernel<1, 2048><<<dim3(gxS, D / 128, 1), 256, 0, stream>>>(
        act, wsdT, nullptr, tokslot, slot_w, g, ye, nullptr, out, D, T, T);
    return;
  }

  // ================= FALLBACK PATH (round-3 proven, chunked) =================
  size_t perTok = (size_t)D * 4 + (size_t)actPerTok * 2 + 4 + 48;
  size_t avail = ws_size > 4096 ? ws_size - 4096 : 0;
  long TcL = (long)(avail / (perTok + 8));
  int Tc = (int)(TcL > T ? T : TcL);
  Tc &= ~63;
  if (Tc < 64) Tc = 64;

  for (int t0 = 0; t0 < T; t0 += Tc) {
    int Tcur = (T - t0 < Tc) ? (T - t0) : Tc;
    const float* hC = h + (size_t)t0 * D;
    float* outC = out + (size_t)t0 * D;

    char* ws = (char*)d_ws;
    size_t off = 0;
    auto alloc = [&](size_t bytes) -> void* { void* p = ws + off; off += rnd(bytes); return p; };
    float* accum = (float*)alloc((size_t)Tc * D * sizeof(float));
    unsigned short* act = (unsigned short*)alloc((size_t)Tc * actPerTok * 2);
    float* g      = (float*)alloc((size_t)Tc * 4);
    int* cnt      = (int*)alloc((size_t)E * 4);
    int* offs     = (int*)alloc((size_t)(E + 1) * 4);
    int* slot_e   = (int*)alloc((size_t)2 * Tc * 4);
    int* slot_pos = (int*)alloc((size_t)2 * Tc * 4);
    float* slot_w = (float*)alloc((size_t)2 * Tc * 4);
    int* rowtok   = (int*)alloc((size_t)2 * Tc * 4);
    float* roww   = (float*)alloc((size_t)2 * Tc * 4);
    int* tokslot  = (int*)alloc((size_t)2 * Tc * 4);

    int gy = (Tcur + 63) / 64;

    zero_i32_kernel<<<1, 64, 0, stream>>>(cnt, E);
    zero_f32_kernel<<<1024, 256, 0, stream>>>(accum, (long)Tcur * D);

    router_kernel<<<Tcur, 64, 0, stream>>>(hC, gate_w, wsg, cnt, slot_e, slot_pos, slot_w, g, D);
    scan_kernel<<<1, 64, 0, stream>>>(cnt, offs, E);
    fill_kernel<<<(2 * Tcur + 255) / 256, 256, 0, stream>>>(slot_e, slot_pos, slot_w, offs,
                                                            rowtok, roww, tokslot, 2 * Tcur, E);
    gemm_act_f32_kernel<true><<<dim3(F / 64, gy, E), 256, 0, stream>>>(
        hC, w_gate, w_up, act, offs, rowtok, D, F, 0, Tcur);
    gemm_comb_f32_kernel<0><<<dim3(D / 64, gy, E), 256, 0, stream>>>(
        act, w_down, offs, rowtok, roww, accum, nullptr, nullptr, F, D, 0, Tcur);
    gemm_act_f32_kernel<false><<<dim3(FS / 64, gy, 1), 256, 0, stream>>>(
        hC, ws_gate, ws_up, act, nullptr, nullptr, D, FS, Tcur, Tcur);
    gemm_comb_f32_kernel<1><<<dim3(D / 64, gy, 1), 256, 0, stream>>>(
        act, ws_down, nullptr, nullptr, nullptr, accum, g, outC, FS, D, Tcur, Tcur);
  }
}

// Round 5
// 1668.056 us; speedup vs baseline: 1.6212x; 1.0339x over previous
//
#include <hip/hip_runtime.h>
#include <hip/hip_bf16.h>

typedef short bf16x8 __attribute__((ext_vector_type(8)));
typedef float f32x4 __attribute__((ext_vector_type(4)));

// f32 -> bf16 round-to-nearest-even, as raw bits
__device__ __forceinline__ unsigned short f2b(float f) {
  union { float f; unsigned u; } v; v.f = f;
  unsigned r = v.u + 0x7FFF + ((v.u >> 16) & 1);
  return (unsigned short)(r >> 16);
}

// bf16 raw bits -> f32
__device__ __forceinline__ float b2f(unsigned short u) {
  union { unsigned u; float f; } v; v.u = ((unsigned)u) << 16;
  return v.f;
}

// async global->LDS, 16B per lane; LDS dest = base + lane*16 (wave-uniform base)
__device__ __forceinline__ void async_b128(const void* g, void* l) {
  __builtin_amdgcn_global_load_lds(
      (const __attribute__((address_space(1))) unsigned int*)g,
      (__attribute__((address_space(3))) unsigned int*)l, 16, 0, 0);
}

// counted waits: loads for the buffer being computed must be done; the next
// buffer's 8 loads/wave may remain in flight across the barrier (T4).
#define WAIT_VM8()    asm volatile("s_waitcnt vmcnt(8)" ::: "memory")
#define WAIT_VM0()    asm volatile("s_waitcnt vmcnt(0)" ::: "memory")
#define SBAR()        __builtin_amdgcn_s_barrier()
#define SCHED_FENCE() __builtin_amdgcn_sched_barrier(0)

// ---------------- zero-fill helpers (no hipMemsetAsync in capture) ----------
__global__ void zero_f32_kernel(float* __restrict__ p, long n) {
  long i = (long)blockIdx.x * blockDim.x + threadIdx.x;
  long stride = (long)gridDim.x * blockDim.x;
  for (; i < n; i += stride) p[i] = 0.f;
}
__global__ void zero_i32_kernel(int* __restrict__ p, int n) {
  int i = blockIdx.x * blockDim.x + threadIdx.x;
  if (i < n) p[i] = 0;
}

// ---------------- preproc: f32 -> bf16 flat convert -------------------------
__global__ __launch_bounds__(256) void convert_bf16_kernel(
    const float* __restrict__ src, unsigned short* __restrict__ dst, long n8) {
  long i = (long)blockIdx.x * blockDim.x + threadIdx.x;
  long stride = (long)gridDim.x * blockDim.x;
  for (; i < n8; i += stride) {
    const float* s = src + i * 8;
    float4 v0 = *(const float4*)s;
    float4 v1 = *(const float4*)(s + 4);
    bf16x8 w;
    w[0] = (short)f2b(v0.x); w[1] = (short)f2b(v0.y); w[2] = (short)f2b(v0.z); w[3] = (short)f2b(v0.w);
    w[4] = (short)f2b(v1.x); w[5] = (short)f2b(v1.y); w[6] = (short)f2b(v1.z); w[7] = (short)f2b(v1.w);
    *(bf16x8*)(dst + i * 8) = w;
  }
}

// ---------------- preproc: f32 [B][R][C] -> bf16 [B][C][R] ------------------
__global__ __launch_bounds__(256) void transpose_convert_kernel(
    const float* __restrict__ srcAll, unsigned short* __restrict__ dstAll,
    int R, int C) {
  const float* src = srcAll + (size_t)blockIdx.z * R * C;
  unsigned short* dst = dstAll + (size_t)blockIdx.z * R * C;
  int c0 = blockIdx.x * 64, r0 = blockIdx.y * 64;
  __shared__ float tile[64][73];
  int t = threadIdx.x;
  int sr = t >> 3;           // 0..31
  int sc = (t & 7) * 8;      // 0..56
#pragma unroll
  for (int rr = 0; rr < 2; ++rr) {
    int row = sr + rr * 32;
    const float* s = src + (size_t)(r0 + row) * C + c0 + sc;
    float4 v0 = *(const float4*)s;
    float4 v1 = *(const float4*)(s + 4);
    tile[row][sc + 0] = v0.x; tile[row][sc + 1] = v0.y;
    tile[row][sc + 2] = v0.z; tile[row][sc + 3] = v0.w;
    tile[row][sc + 4] = v1.x; tile[row][sc + 5] = v1.y;
    tile[row][sc + 6] = v1.z; tile[row][sc + 7] = v1.w;
  }
  __syncthreads();
#pragma unroll
  for (int pp = 0; pp < 2; ++pp) {
    int cc = sr + pp * 32;
    int rc = sc;
    bf16x8 w;
#pragma unroll
    for (int j = 0; j < 8; ++j) w[j] = (short)f2b(tile[rc + j][cc]);
    *(bf16x8*)(dst + (size_t)(c0 + cc) * R + r0 + rc) = w;
  }
}

// ---------------- Router ----------------------------------------------------
__global__ __launch_bounds__(64) void router_kernel(
    const float* __restrict__ h, const float* __restrict__ gate_w,
    const float* __restrict__ wsg,
    int* __restrict__ cnt, int* __restrict__ slot_e, int* __restrict__ slot_pos,
    float* __restrict__ slot_w, float* __restrict__ gout, int D) {
  int t = blockIdx.x;
  int lane = threadIdx.x;
  float acc[8] = {0.f, 0.f, 0.f, 0.f, 0.f, 0.f, 0.f, 0.f};
  float aw = 0.f;
  const float* hrow = h + (size_t)t * D;
  for (int d = lane; d < D; d += 64) {
    float hv = hrow[d];
    float4 g0 = *(const float4*)(gate_w + (size_t)d * 8);
    float4 g1 = *(const float4*)(gate_w + (size_t)d * 8 + 4);
    acc[0] += hv * g0.x; acc[1] += hv * g0.y; acc[2] += hv * g0.z; acc[3] += hv * g0.w;
    acc[4] += hv * g1.x; acc[5] += hv * g1.y; acc[6] += hv * g1.z; acc[7] += hv * g1.w;
    aw += hv * wsg[d];
  }
#pragma unroll
  for (int off = 32; off > 0; off >>= 1) {
#pragma unroll
    for (int e = 0; e < 8; ++e) acc[e] += __shfl_down(acc[e], off);
    aw += __shfl_down(aw, off);
  }
  if (lane == 0) {
    int e0 = 0; float m0v = acc[0];
#pragma unroll
    for (int e = 1; e < 8; ++e) if (acc[e] > m0v) { m0v = acc[e]; e0 = e; }
    int e1 = -1; float m1v = -3.4e38f;
#pragma unroll
    for (int e = 0; e < 8; ++e) if (e != e0 && acc[e] > m1v) { m1v = acc[e]; e1 = e; }
    if (e1 < 0) e1 = (e0 + 1) & 7;
    float r = __expf(m1v - m0v);
    float w0 = 1.f / (1.f + r);
    float w1 = 1.f - w0;
    int p;
    p = atomicAdd(&cnt[e0], 1);
    slot_e[2 * t] = e0; slot_pos[2 * t] = p; slot_w[2 * t] = w0;
    p = atomicAdd(&cnt[e1], 1);
    slot_e[2 * t + 1] = e1; slot_pos[2 * t + 1] = p; slot_w[2 * t + 1] = w1;
    gout[t] = 1.f / (1.f + __expf(-aw));
  }
}

__global__ void scan_kernel(const int* __restrict__ cnt, int* __restrict__ offs, int E) {
  if (threadIdx.x == 0 && blockIdx.x == 0) {
    int s = 0;
    for (int e = 0; e < E; ++e) { offs[e] = s; s += cnt[e]; }
    offs[E] = s;
  }
}

// fill: forward map row->token/weight AND inverse map slot->row
__global__ void fill_kernel(const int* __restrict__ slot_e, const int* __restrict__ slot_pos,
                            const float* __restrict__ slot_w, const int* __restrict__ offs,
                            int* __restrict__ rowtok, float* __restrict__ roww,
                            int* __restrict__ tokslot, int n2T, int E) {
  int i = blockIdx.x * blockDim.x + threadIdx.x;
  if (i < n2T) {
    int e = slot_e[i];
    if (e < 0) e = 0; if (e >= E) e = E - 1;
    int row = offs[e] + slot_pos[i];
    if (row < 0) row = 0; if (row >= n2T) row = n2T - 1;
    rowtok[row] = i >> 1;
    roww[row] = slot_w[i];
    tokslot[i] = row;
  }
}

// ============================================================================
// FAST PATH v8: v6 geometry (128-row tiles, 256 threads, 64 KB LDS, 2 blk/CU)
// + T3/T4 counted-vmcnt pipeline: next-tile global_load_lds stays IN FLIGHT
// across the barrier (s_waitcnt vmcnt(8), never 0 in the main loop).
// Exactly 8 global_load_lds per wave per K-step in BOTH kernels, no other
// VMEM ops inside the loop, VGPR<=96 (no spill scratch) => count is exact.
// LDS layout [rowblock8][kgroup][row%8] (16B chunks), conflict-free ds_read_b128.
// Expert down-proj writes per-slot ye[2T][D] bf16 (NO atomics); shared down-proj
// epilogue fuses the 2-way gather combine and writes out once.
// ============================================================================
#define LDSOFF(row, kg) (((row) >> 3) * 512 + (kg) * 64 + ((row) & 7) * 8)

// ---- act: C = silu(A Bg^T) * (A Bu^T); tile 128(m) x 64(n), BK=64 ----------
template <bool EXPERT, int K>
__global__ __launch_bounds__(256) void gemm_act3_kernel(
    const unsigned short* __restrict__ hb,     // bf16 [T][K]
    const unsigned short* __restrict__ BgT,    // bf16 [(E)][N][K]
    const unsigned short* __restrict__ BuT,    // bf16 [(E)][N][K]
    unsigned short* __restrict__ actOut,       // bf16 [rows][N]
    const int* __restrict__ offs, const int* __restrict__ rowtok,
    int N, int rowsDirect, int T) {
  int e = EXPERT ? blockIdx.z : 0;
  int base = 0, cnt = rowsDirect;
  if (EXPERT) { base = offs[e]; cnt = offs[e + 1] - base; }
  int m0 = blockIdx.x * 128;
  if (m0 >= cnt) return;
  int n0 = blockIdx.y * 64;

  const unsigned short* Bg = BgT + (size_t)e * N * K;
  const unsigned short* Bu = BuT + (size_t)e * N * K;

  __shared__ __align__(16) unsigned short As[2][128 * 64];   // 2 x 16 KB
  __shared__ __align__(16) unsigned short Bgs[2][64 * 64];   // 2 x 8 KB
  __shared__ __align__(16) unsigned short Bus[2][64 * 64];   // 2 x 8 KB -> 64 KB

  int tid = threadIdx.x, lane = tid & 63, wave = tid >> 6;
  int r8 = lane & 7, kg = lane >> 3;
  int quad = lane >> 4, l16 = lane & 15;

  // staging sources: wave w stages A rows [w*32, w*32+32), B rows [w*16, w*16+16)
  const unsigned short* aSrc[4];
#pragma unroll
  for (int t = 0; t < 4; ++t) {
    int gr = m0 + wave * 32 + t * 8 + r8;
    if (gr >= cnt) gr = cnt - 1;
    int tok = EXPERT ? rowtok[base + gr] : gr;
    if (tok < 0) tok = 0; if (tok >= T) tok = T - 1;
    aSrc[t] = hb + (size_t)tok * K + kg * 8;
  }
  const unsigned short* gSrc[2];
  const unsigned short* uSrc[2];
#pragma unroll
  for (int t = 0; t < 2; ++t) {
    int n = n0 + wave * 16 + t * 8 + r8;
    gSrc[t] = Bg + (size_t)n * K + kg * 8;
    uSrc[t] = Bu + (size_t)n * K + kg * 8;
  }

  // exactly 8 global_load_lds per wave
  auto stage = [&](int buf, int kt) {
#pragma unroll
    for (int t = 0; t < 4; ++t) async_b128(aSrc[t] + kt, As[buf] + (wave * 4 + t) * 512);
#pragma unroll
    for (int t = 0; t < 2; ++t) {
      async_b128(gSrc[t] + kt, Bgs[buf] + (wave * 2 + t) * 512);
      async_b128(uSrc[t] + kt, Bus[buf] + (wave * 2 + t) * 512);
    }
  };

  f32x4 accG[2][4] = {};
  f32x4 accU[2][4] = {};

  stage(0, 0);
  int cur = 0;
  for (int kt = 0; kt < K; kt += 64) {
    bool more = (kt + 64 < K);
    if (more) stage(cur ^ 1, kt + 64);   // 8 loads fly across the barrier
    if (more) { WAIT_VM8(); } else { WAIT_VM0(); }  // cur's loads landed
    SBAR();
    SCHED_FENCE();
#pragma unroll
    for (int ks = 0; ks < 2; ++ks) {
      int kq = ks * 4 + quad;
      bf16x8 a[2], bg[4], bu[4];
#pragma unroll
      for (int mi = 0; mi < 2; ++mi) {
        int m = wave * 32 + mi * 16 + l16;
        a[mi] = *(const bf16x8*)(As[cur] + LDSOFF(m, kq));
      }
#pragma unroll
      for (int nj = 0; nj < 4; ++nj) {
        int n = nj * 16 + l16;
        bg[nj] = *(const bf16x8*)(Bgs[cur] + LDSOFF(n, kq));
        bu[nj] = *(const bf16x8*)(Bus[cur] + LDSOFF(n, kq));
      }
#pragma unroll
      for (int mi = 0; mi < 2; ++mi)
#pragma unroll
        for (int nj = 0; nj < 4; ++nj) {
          accG[mi][nj] = __builtin_amdgcn_mfma_f32_16x16x32_bf16(a[mi], bg[nj], accG[mi][nj], 0, 0, 0);
          accU[mi][nj] = __builtin_amdgcn_mfma_f32_16x16x32_bf16(a[mi], bu[nj], accU[mi][nj], 0, 0, 0);
        }
    }
    SCHED_FENCE();
    SBAR();  // all waves done reading cur; next iter stages into cur
    cur ^= 1;
  }

#pragma unroll
  for (int mi = 0; mi < 2; ++mi)
#pragma unroll
    for (int nj = 0; nj < 4; ++nj)
#pragma unroll
      for (int r = 0; r < 4; ++r) {
        int grow = m0 + wave * 32 + mi * 16 + quad * 4 + r;
        if (grow < cnt) {
          int col = n0 + nj * 16 + l16;
          float gv = accG[mi][nj][r], uv = accU[mi][nj][r];
          float sv = gv / (1.f + __expf(-gv)) * uv;
          actOut[(size_t)(base + grow) * N + col] = f2b(sv);
        }
      }
}

// ---- comb: down-proj; tile 128 x 128, BK=64, counted-vmcnt pipeline --------
// MODE 0: expert down-proj -> ye[2T][N] bf16 (plain coalesced stores, no atomics)
// MODE 1: shared down-proj + fused final combine:
//         out[t][c] = gsig[t]*v + w0*ye[r0][c] + w1*ye[r1][c]   (writes out once)
template <int MODE, int K>
__global__ __launch_bounds__(256) void gemm_comb3_kernel(
    const unsigned short* __restrict__ A,      // bf16 [rows][K] contiguous
    const unsigned short* __restrict__ BT,     // bf16 [(E)][N][K]
    const int* __restrict__ offs,
    const int* __restrict__ tokslot,           // [2T] slot -> compacted row
    const float* __restrict__ slot_w,          // [2T] slot weight
    const float* __restrict__ gsig,            // [T] shared sigmoid gate
    const unsigned short* __restrict__ ye_in,  // bf16 [2T][N] (MODE 1)
    unsigned short* __restrict__ ye_out,       // bf16 [2T][N] (MODE 0)
    float* __restrict__ out,                   // f32 [T][N]   (MODE 1)
    int N, int rowsDirect, int T) {
  int e = (MODE == 0) ? blockIdx.z : 0;
  int base = 0, cnt = rowsDirect;
  if (MODE == 0) { base = offs[e]; cnt = offs[e + 1] - base; }
  int m0 = blockIdx.x * 128;
  if (m0 >= cnt) return;
  int n0 = blockIdx.y * 128;

  const unsigned short* B = BT + (size_t)e * N * K;

  __shared__ __align__(16) unsigned short As[2][128 * 64];   // 2 x 16 KB
  __shared__ __align__(16) unsigned short Bs[2][128 * 64];   // 2 x 16 KB -> 64 KB

  int tid = threadIdx.x, lane = tid & 63, wave = tid >> 6;
  int r8 = lane & 7, kg = lane >> 3;
  int quad = lane >> 4, l16 = lane & 15;
  int mBase = (wave >> 1) * 64, nBase = (wave & 1) * 64;

  const unsigned short* aSrc[4];
  const unsigned short* bSrc[4];
#pragma unroll
  for (int t = 0; t < 4; ++t) {
    int gr = m0 + wave * 32 + t * 8 + r8;
    if (gr >= cnt) gr = cnt - 1;
    aSrc[t] = A + (size_t)(base + gr) * K + kg * 8;
    int n = n0 + wave * 32 + t * 8 + r8;
    bSrc[t] = B + (size_t)n * K + kg * 8;
  }

  // exactly 8 global_load_lds per wave
  auto stage = [&](int buf, int kt) {
#pragma unroll
    for (int t = 0; t < 4; ++t) {
      async_b128(aSrc[t] + kt, As[buf] + (wave * 4 + t) * 512);
      async_b128(bSrc[t] + kt, Bs[buf] + (wave * 4 + t) * 512);
    }
  };

  f32x4 acc[4][4] = {};

  stage(0, 0);
  int cur = 0;
  for (int kt = 0; kt < K; kt += 64) {
    bool more = (kt + 64 < K);
    if (more) stage(cur ^ 1, kt + 64);
    if (more) { WAIT_VM8(); } else { WAIT_VM0(); }
    SBAR();
    SCHED_FENCE();
#pragma unroll
    for (int ks = 0; ks < 2; ++ks) {
      int kq = ks * 4 + quad;
      bf16x8 a[4], b[4];
#pragma unroll
      for (int mi = 0; mi < 4; ++mi) {
        int m = mBase + mi * 16 + l16;
        a[mi] = *(const bf16x8*)(As[cur] + LDSOFF(m, kq));
      }
#pragma unroll
      for (int nj = 0; nj < 4; ++nj) {
        int n = nBase + nj * 16 + l16;
        b[nj] = *(const bf16x8*)(Bs[cur] + LDSOFF(n, kq));
      }
#pragma unroll
      for (int mi = 0; mi < 4; ++mi)
#pragma unroll
        for (int nj = 0; nj < 4; ++nj)
          acc[mi][nj] = __builtin_amdgcn_mfma_f32_16x16x32_bf16(a[mi], b[nj], acc[mi][nj], 0, 0, 0);
    }
    SCHED_FENCE();
    SBAR();
    cur ^= 1;
  }

#pragma unroll
  for (int mi = 0; mi < 4; ++mi)
#pragma unroll
    for (int r = 0; r < 4; ++r) {
      int grow = m0 + mBase + mi * 16 + quad * 4 + r;
      if (grow < cnt) {
        if (MODE == 0) {
#pragma unroll
          for (int nj = 0; nj < 4; ++nj) {
            int col = n0 + nBase + nj * 16 + l16;
            ye_out[(size_t)(base + grow) * N + col] = f2b(acc[mi][nj][r]);
          }
        } else {
          int r0 = tokslot[2 * grow], r1 = tokslot[2 * grow + 1];
          float w0 = slot_w[2 * grow], w1 = slot_w[2 * grow + 1];
          float gv = gsig[grow];
#pragma unroll
          for (int nj = 0; nj < 4; ++nj) {
            int col = n0 + nBase + nj * 16 + l16;
            float v = acc[mi][nj][r];
            float e0 = b2f(ye_in[(size_t)r0 * N + col]);
            float e1 = b2f(ye_in[(size_t)r1 * N + col]);
            out[(size_t)grow * N + col] = gv * v + w0 * e0 + w1 * e1;
          }
        }
      }
    }
}

// ============================================================================
// FALLBACK PATH (round-3 proven): f32-staging LDS GEMMs + token chunking.
// ============================================================================
template <bool EXPERT>
__global__ __launch_bounds__(256) void gemm_act_f32_kernel(
    const float* __restrict__ X, const float* __restrict__ BgAll,
    const float* __restrict__ BuAll, unsigned short* __restrict__ actOut,
    const int* __restrict__ offs, const int* __restrict__ rowtok,
    int K, int N, int rowsDirect, int maxTok) {
  int e = EXPERT ? blockIdx.z : 0;
  int base = 0, cnt = rowsDirect;
  if (EXPERT) { base = offs[e]; cnt = offs[e + 1] - base; }
  int m0 = blockIdx.y * 64;
  if (m0 >= cnt) return;
  int n0 = blockIdx.x * 64;
  const float* Bg = BgAll + (size_t)e * K * N;
  const float* Bu = BuAll + (size_t)e * K * N;
  __shared__ __align__(16) short As[64][72];
  __shared__ __align__(16) short Bgs[64][72];
  __shared__ __align__(16) short Bus[64][72];
  int tid = threadIdx.x, lane = tid & 63, wave = tid >> 6;
  int quad = lane >> 4, l16 = lane & 15;
  int mBase = (wave >> 1) * 32, nBase = (wave & 1) * 32;
  f32x4 accG[2][2] = {};
  f32x4 accU[2][2] = {};
  int sr = tid >> 3, sc = (tid & 7) * 8;
  size_t aRowOff[2];
#pragma unroll
  for (int rr = 0; rr < 2; ++rr) {
    int gr = m0 + sr + rr * 32;
    if (gr >= cnt) gr = cnt - 1;
    int tokenRow = EXPERT ? rowtok[base + gr] : gr;
    if (tokenRow < 0) tokenRow = 0;
    if (tokenRow >= maxTok) tokenRow = maxTok - 1;
    aRowOff[rr] = (size_t)tokenRow * K;
  }
  for (int kt = 0; kt < K; kt += 64) {
#pragma unroll
    for (int rr = 0; rr < 2; ++rr) {
      int r = sr + rr * 32;
      const float* src = X + aRowOff[rr] + kt + sc;
      float4 v0 = *(const float4*)src;
      float4 v1 = *(const float4*)(src + 4);
      bf16x8 w;
      w[0] = (short)f2b(v0.x); w[1] = (short)f2b(v0.y); w[2] = (short)f2b(v0.z); w[3] = (short)f2b(v0.w);
      w[4] = (short)f2b(v1.x); w[5] = (short)f2b(v1.y); w[6] = (short)f2b(v1.z); w[7] = (short)f2b(v1.w);
      *(bf16x8*)&As[r][sc] = w;
    }
#pragma unroll
    for (int rr = 0; rr < 2; ++rr) {
      int kk = sr + rr * 32;
      const float* bg = Bg + (size_t)(kt + kk) * N + n0 + sc;
      const float* bu = Bu + (size_t)(kt + kk) * N + n0 + sc;
      float4 g0 = *(const float4*)bg; float4 g1 = *(const float4*)(bg + 4);
      float4 u0 = *(const float4*)bu; float4 u1 = *(const float4*)(bu + 4);
      Bgs[sc + 0][kk] = (short)f2b(g0.x); Bgs[sc + 1][kk] = (short)f2b(g0.y);
      Bgs[sc + 2][kk] = (short)f2b(g0.z); Bgs[sc + 3][kk] = (short)f2b(g0.w);
      Bgs[sc + 4][kk] = (short)f2b(g1.x); Bgs[sc + 5][kk] = (short)f2b(g1.y);
      Bgs[sc + 6][kk] = (short)f2b(g1.z); Bgs[sc + 7][kk] = (short)f2b(g1.w);
      Bus[sc + 0][kk] = (short)f2b(u0.x); Bus[sc + 1][kk] = (short)f2b(u0.y);
      Bus[sc + 2][kk] = (short)f2b(u0.z); Bus[sc + 3][kk] = (short)f2b(u0.w);
      Bus[sc + 4][kk] = (short)f2b(u1.x); Bus[sc + 5][kk] = (short)f2b(u1.y);
      Bus[sc + 6][kk] = (short)f2b(u1.z); Bus[sc + 7][kk] = (short)f2b(u1.w);
    }
    __syncthreads();
#pragma unroll
    for (int ks = 0; ks < 2; ++ks) {
      bf16x8 a[2], bg[2], bu[2];
#pragma unroll
      for (int i = 0; i < 2; ++i)
        a[i] = *(const bf16x8*)&As[mBase + i * 16 + l16][ks * 32 + quad * 8];
#pragma unroll
      for (int i = 0; i < 2; ++i) {
        bg[i] = *(const bf16x8*)&Bgs[nBase + i * 16 + l16][ks * 32 + quad * 8];
        bu[i] = *(const bf16x8*)&Bus[nBase + i * 16 + l16][ks * 32 + quad * 8];
      }
#pragma unroll
      for (int i = 0; i < 2; ++i)
#pragma unroll
        for (int j = 0; j < 2; ++j) {
          accG[i][j] = __builtin_amdgcn_mfma_f32_16x16x32_bf16(a[i], bg[j], accG[i][j], 0, 0, 0);
          accU[i][j] = __builtin_amdgcn_mfma_f32_16x16x32_bf16(a[i], bu[j], accU[i][j], 0, 0, 0);
        }
    }
    __syncthreads();
  }
#pragma unroll
  for (int i = 0; i < 2; ++i)
#pragma unroll
    for (int j = 0; j < 2; ++j)
#pragma unroll
      for (int r = 0; r < 4; ++r) {
        int row = mBase + i * 16 + quad * 4 + r;
        int grow = m0 + row;
        if (grow < cnt) {
          int col = n0 + nBase + j * 16 + l16;
          float gv = accG[i][j][r], uv = accU[i][j][r];
          float sv = gv / (1.f + __expf(-gv)) * uv;
          actOut[(size_t)(base + grow) * N + col] = f2b(sv);
        }
      }
}

template <int MODE>
__global__ __launch_bounds__(256) void gemm_comb_f32_kernel(
    const unsigned short* __restrict__ A, const float* __restrict__ BAll,
    const int* __restrict__ offs, const int* __restrict__ rowtok,
    const float* __restrict__ roww, float* __restrict__ accum,
    const float* __restrict__ gsig, float* __restrict__ out,
    int K, int N, int rowsDirect, int maxTok) {
  int e = (MODE == 0) ? blockIdx.z : 0;
  int base = 0, cnt = rowsDirect;
  if (MODE == 0) { base = offs[e]; cnt = offs[e + 1] - base; }
  int m0 = blockIdx.y * 64;
  if (m0 >= cnt) return;
  int n0 = blockIdx.x * 64;
  const float* B = BAll + (size_t)e * K * N;
  __shared__ __align__(16) short As[64][72];
  __shared__ __align__(16) short Bs[64][72];
  int tid = threadIdx.x, lane = tid & 63, wave = tid >> 6;
  int quad = lane >> 4, l16 = lane & 15;
  int mBase = (wave >> 1) * 32, nBase = (wave & 1) * 32;
  f32x4 acc[2][2] = {};
  int sr = tid >> 3, sc = (tid & 7) * 8;
  size_t aRowOff[2];
#pragma unroll
  for (int rr = 0; rr < 2; ++rr) {
    int gr = m0 + sr + rr * 32;
    if (gr >= cnt) gr = cnt - 1;
    aRowOff[rr] = (size_t)(base + gr) * K;
  }
  for (int kt = 0; kt < K; kt += 64) {
#pragma unroll
    for (int rr = 0; rr < 2; ++rr) {
      int r = sr + rr * 32;
      *(bf16x8*)&As[r][sc] = *(const bf16x8*)(A + aRowOff[rr] + kt + sc);
    }
#pragma unroll
    for (int rr = 0; rr < 2; ++rr) {
      int kk = sr + rr * 32;
      const float* bp = B + (size_t)(kt + kk) * N + n0 + sc;
      float4 b0 = *(const float4*)bp; float4 b1 = *(const float4*)(bp + 4);
      Bs[sc + 0][kk] = (short)f2b(b0.x); Bs[sc + 1][kk] = (short)f2b(b0.y);
      Bs[sc + 2][kk] = (short)f2b(b0.z); Bs[sc + 3][kk] = (short)f2b(b0.w);
      Bs[sc + 4][kk] = (short)f2b(b1.x); Bs[sc + 5][kk] = (short)f2b(b1.y);
      Bs[sc + 6][kk] = (short)f2b(b1.z); Bs[sc + 7][kk] = (short)f2b(b1.w);
    }
    __syncthreads();
#pragma unroll
    for (int ks = 0; ks < 2; ++ks) {
      bf16x8 a[2], b[2];
#pragma unroll
      for (int i = 0; i < 2; ++i)
        a[i] = *(const bf16x8*)&As[mBase + i * 16 + l16][ks * 32 + quad * 8];
#pragma unroll
      for (int i = 0; i < 2; ++i)
        b[i] = *(const bf16x8*)&Bs[nBase + i * 16 + l16][ks * 32 + quad * 8];
#pragma unroll
      for (int i = 0; i < 2; ++i)
#pragma unroll
        for (int j = 0; j < 2; ++j)
          acc[i][j] = __builtin_amdgcn_mfma_f32_16x16x32_bf16(a[i], b[j], acc[i][j], 0, 0, 0);
    }
    __syncthreads();
  }
#pragma unroll
  for (int i = 0; i < 2; ++i)
#pragma unroll
    for (int j = 0; j < 2; ++j)
#pragma unroll
      for (int r = 0; r < 4; ++r) {
        int row = mBase + i * 16 + quad * 4 + r;
        int grow = m0 + row;
        if (grow < cnt) {
          int col = n0 + nBase + j * 16 + l16;
          float v = acc[i][j][r];
          if (MODE == 0) {
            int tok = rowtok[base + grow];
            if (tok < 0) tok = 0;
            if (tok >= maxTok) tok = maxTok - 1;
            atomicAdd(&accum[(size_t)tok * N + col], roww[base + grow] * v);
          } else {
            out[(size_t)grow * N + col] = accum[(size_t)grow * N + col] + gsig[grow] * v;
          }
        }
      }
}

// ---------------------------------------------------------------------------
extern "C" void kernel_launch(void* const* d_in, const int* in_sizes, int n_in,
                              void* d_out, int out_size, void* d_ws, size_t ws_size,
                              hipStream_t stream) {
  const float* h       = (const float*)d_in[0];
  const float* gate_w  = (const float*)d_in[1];
  const float* w_gate  = (const float*)d_in[2];
  const float* w_up    = (const float*)d_in[3];
  const float* w_down  = (const float*)d_in[4];
  const float* ws_gate = (const float*)d_in[5];
  const float* ws_up   = (const float*)d_in[6];
  const float* ws_down = (const float*)d_in[7];
  const float* wsg     = (const float*)d_in[8];
  float* out = (float*)d_out;

  const int D  = in_sizes[8];            // 2048
  const int T  = in_sizes[0] / D;        // 8192
  const int E  = in_sizes[1] / D;        // 8
  const int F  = in_sizes[2] / (E * D);  // 1024
  const int FS = in_sizes[5] / D;        // 2048
  (void)n_in; (void)out_size;

  const int actPerTok = (2 * F > FS ? 2 * F : FS);

  size_t al = 256;
  auto rnd = [&](size_t b) { return (b + al - 1) & ~(al - 1); };
  size_t need = 0;
  need += rnd((size_t)T * D * 2);            // hb
  need += rnd((size_t)E * D * F * 2) * 3;    // wgT, wuT, wdT
  need += rnd((size_t)D * FS * 2) * 3;       // wsgT, wsuT, wsdT
  need += rnd((size_t)T * actPerTok * 2);    // act
  need += rnd((size_t)T * 4);                // g
  need += rnd((size_t)E * 4) + rnd((size_t)(E + 1) * 4);
  need += rnd((size_t)2 * T * 4) * 6;        // slot_e/pos/w, rowtok, roww, tokslot

  bool shapeOK = (D == 2048 && F == 1024 && FS == 2048 && E == 8 && (T % 128) == 0);

  if (shapeOK && ws_size >= need) {
    // ================= FAST PATH v8 =================
    char* ws = (char*)d_ws;
    size_t off = 0;
    auto alloc = [&](size_t bytes) -> void* { void* p = ws + off; off += rnd(bytes); return p; };
    unsigned short* hb   = (unsigned short*)alloc((size_t)T * D * 2);
    unsigned short* wgT  = (unsigned short*)alloc((size_t)E * D * F * 2);
    unsigned short* wuT  = (unsigned short*)alloc((size_t)E * D * F * 2);
    unsigned short* wdT  = (unsigned short*)alloc((size_t)E * D * F * 2);
    unsigned short* wsgT = (unsigned short*)alloc((size_t)D * FS * 2);
    unsigned short* wsuT = (unsigned short*)alloc((size_t)D * FS * 2);
    unsigned short* wsdT = (unsigned short*)alloc((size_t)D * FS * 2);
    unsigned short* act  = (unsigned short*)alloc((size_t)T * actPerTok * 2);
    float* g      = (float*)alloc((size_t)T * 4);
    int* cnt      = (int*)alloc((size_t)E * 4);
    int* offs     = (int*)alloc((size_t)(E + 1) * 4);
    int* slot_e   = (int*)alloc((size_t)2 * T * 4);
    int* slot_pos = (int*)alloc((size_t)2 * T * 4);
    float* slot_w = (float*)alloc((size_t)2 * T * 4);
    int* rowtok   = (int*)alloc((size_t)2 * T * 4);
    float* roww   = (float*)alloc((size_t)2 * T * 4);
    int* tokslot  = (int*)alloc((size_t)2 * T * 4);

    // ye[2T][D] bf16 aliases wgT+wuT: 2*T*D shorts == 2*(E*D*F) shorts, and
    // wgT/wuT are dead after gemm_act3<true> completes (stream-ordered).
    unsigned short* ye = wgT;

    zero_i32_kernel<<<1, 64, 0, stream>>>(cnt, E);

    convert_bf16_kernel<<<2048, 256, 0, stream>>>(h, hb, (long)T * D / 8);
    transpose_convert_kernel<<<dim3(F / 64, D / 64, E), 256, 0, stream>>>(w_gate, wgT, D, F);
    transpose_convert_kernel<<<dim3(F / 64, D / 64, E), 256, 0, stream>>>(w_up, wuT, D, F);
    transpose_convert_kernel<<<dim3(D / 64, F / 64, E), 256, 0, stream>>>(w_down, wdT, F, D);
    transpose_convert_kernel<<<dim3(FS / 64, D / 64, 1), 256, 0, stream>>>(ws_gate, wsgT, D, FS);
    transpose_convert_kernel<<<dim3(FS / 64, D / 64, 1), 256, 0, stream>>>(ws_up, wsuT, D, FS);
    transpose_convert_kernel<<<dim3(D / 64, FS / 64, 1), 256, 0, stream>>>(ws_down, wsdT, FS, D);

    router_kernel<<<T, 64, 0, stream>>>(h, gate_w, wsg, cnt, slot_e, slot_pos, slot_w, g, D);
    scan_kernel<<<1, 64, 0, stream>>>(cnt, offs, E);
    fill_kernel<<<(2 * T + 255) / 256, 256, 0, stream>>>(slot_e, slot_pos, slot_w, offs,
                                                         rowtok, roww, tokslot, 2 * T, E);

    int gxE = (2 * T) / 128;  // 128: covers worst-case per-expert cnt (= 2T)
    int gxS = T / 128;        // 64
    // Expert gate/up + silu*mul -> act[2T, F]
    gemm_act3_kernel<true, 2048><<<dim3(gxE, F / 64, E), 256, 0, stream>>>(
        hb, wgT, wuT, act, offs, rowtok, F, 0, T);
    // Expert down-proj -> ye[2T, D] bf16 (no atomics; overwrites wgT/wuT)
    gemm_comb3_kernel<0, 1024><<<dim3(gxE, D / 128, E), 256, 0, stream>>>(
        act, wdT, offs, nullptr, nullptr, nullptr, nullptr, ye, nullptr, D, 0, T);
    // Shared gate/up -> act[T, FS]
    gemm_act3_kernel<false, 2048><<<dim3(gxS, FS / 64, 1), 256, 0, stream>>>(
        hb, wsgT, wsuT, act, nullptr, nullptr, FS, T, T);
    // Shared down-proj + fused gather-combine: out = g*shared + w0*ye[r0] + w1*ye[r1]
    gemm_comb3_kernel<1, 2048><<<dim3(gxS, D / 128, 1), 256, 0, stream>>>(
        act, wsdT, nullptr, tokslot, slot_w, g, ye, nullptr, out, D, T, T);
    return;
  }

  // ================= FALLBACK PATH (round-3 proven, chunked) =================
  size_t perTok = (size_t)D * 4 + (size_t)actPerTok * 2 + 4 + 48;
  size_t avail = ws_size > 4096 ? ws_size - 4096 : 0;
  long TcL = (long)(avail / (perTok + 8));
  int Tc = (int)(TcL > T ? T : TcL);
  Tc &= ~63;
  if (Tc < 64) Tc = 64;

  for (int t0 = 0; t0 < T; t0 += Tc) {
    int Tcur = (T - t0 < Tc) ? (T - t0) : Tc;
    const float* hC = h + (size_t)t0 * D;
    float* outC = out + (size_t)t0 * D;

    char* ws = (char*)d_ws;
    size_t off = 0;
    auto alloc = [&](size_t bytes) -> void* { void* p = ws + off; off += rnd(bytes); return p; };
    float* accum = (float*)alloc((size_t)Tc * D * sizeof(float));
    unsigned short* act = (unsigned short*)alloc((size_t)Tc * actPerTok * 2);
    float* g      = (float*)alloc((size_t)Tc * 4);
    int* cnt      = (int*)alloc((size_t)E * 4);
    int* offs     = (int*)alloc((size_t)(E + 1) * 4);
    int* slot_e   = (int*)alloc((size_t)2 * Tc * 4);
    int* slot_pos = (int*)alloc((size_t)2 * Tc * 4);
    float* slot_w = (float*)alloc((size_t)2 * Tc * 4);
    int* rowtok   = (int*)alloc((size_t)2 * Tc * 4);
    float* roww   = (float*)alloc((size_t)2 * Tc * 4);
    int* tokslot  = (int*)alloc((size_t)2 * Tc * 4);

    int gy = (Tcur + 63) / 64;

    zero_i32_kernel<<<1, 64, 0, stream>>>(cnt, E);
    zero_f32_kernel<<<1024, 256, 0, stream>>>(accum, (long)Tcur * D);

    router_kernel<<<Tcur, 64, 0, stream>>>(hC, gate_w, wsg, cnt, slot_e, slot_pos, slot_w, g, D);
    scan_kernel<<<1, 64, 0, stream>>>(cnt, offs, E);
    fill_kernel<<<(2 * Tcur + 255) / 256, 256, 0, stream>>>(slot_e, slot_pos, slot_w, offs,
                                                            rowtok, roww, tokslot, 2 * Tcur, E);
    gemm_act_f32_kernel<true><<<dim3(F / 64, gy, E), 256, 0, stream>>>(
        hC, w_gate, w_up, act, offs, rowtok, D, F, 0, Tcur);
    gemm_comb_f32_kernel<0><<<dim3(D / 64, gy, E), 256, 0, stream>>>(
        act, w_down, offs, rowtok, roww, accum, nullptr, nullptr, F, D, 0, Tcur);
    gemm_act_f32_kernel<false><<<dim3(FS / 64, gy, 1), 256, 0, stream>>>(
        hC, ws_gate, ws_up, act, nullptr, nullptr, D, FS, Tcur, Tcur);
    gemm_comb_f32_kernel<1><<<dim3(D / 64, gy, 1), 256, 0, stream>>>(
        act, ws_down, nullptr, nullptr, nullptr, accum, g, outC, FS, D, Tcur, Tcur);
  }
}